// Round 4
// baseline (1755.605 us; speedup 1.0000x reference)
//
#include <hip/hip_runtime.h>
#include <hip/hip_cooperative_groups.h>

// SARDecoder on MI355X (gfx950). Dtype-robust (runtime bf16-vs-fp32 detect).
//
// Round-4 changes:
//  - conv_fproj: zero-padded feature map + global_load_lds(16B) staging into
//    XOR-swizzled LDS tiles (lane-ordered dest requirement), XCD-friendly bid swizzle
//  - LSTM recurrence: single persistent cooperative kernel, grid.sync() between steps

namespace cg = cooperative_groups;

typedef __bf16 bf16;
typedef bf16 bf16x8 __attribute__((ext_vector_type(8)));
typedef float f32x4 __attribute__((ext_vector_type(4)));

#define MFMA16(a, b, c) __builtin_amdgcn_mfma_f32_16x16x32_bf16((a), (b), (c), 0, 0, 0)

__device__ __forceinline__ float b2f(unsigned short u) {
    return __uint_as_float(((unsigned int)u) << 16);
}
__device__ __forceinline__ unsigned short f2b(float f) {
    unsigned int x = __float_as_uint(f);
    unsigned int r = (x + 0x7fffu + ((x >> 16) & 1u)) >> 16;   // RNE
    return (unsigned short)r;
}
__device__ __forceinline__ float tanh_fast(float x) {
    const float e = exp2f(2.885390082f * x);                   // 2/ln2
    return 1.0f - 2.0f * __builtin_amdgcn_rcpf(e + 1.0f);
}
__device__ __forceinline__ float sig_fast(float x) {
    return __builtin_amdgcn_rcpf(1.0f + exp2f(-1.44269504f * x));
}
// async 16B/lane global->LDS. lds dest is wave-uniform base + lane*16.
__device__ __forceinline__ void gl16(const ushort* g, ushort* l) {
    __builtin_amdgcn_global_load_lds(
        (const __attribute__((address_space(1))) void*)g,
        (__attribute__((address_space(3))) void*)l, 16, 0, 0);
}

// ------------------------------------------------------------ dtype detect
__global__ void detect_dtype(const void* __restrict__ feat, int* __restrict__ flag) {
    if (threadIdx.x == 0 && blockIdx.x == 0) {
        const ushort* u = (const ushort*)feat;
        int cnt = 0;
        for (int i = 0; i < 128; i += 2) {
            const int e = (u[i] >> 7) & 0xFF;
            if (e >= 96 && e <= 150) ++cnt;
        }
        *flag = (cnt >= 40) ? 0 : 1;
    }
}

// ------------------------------------------------------------ converters
__global__ __launch_bounds__(256) void cvt_bf16(
    const void* __restrict__ src, ushort* __restrict__ dst, int n,
    const int* __restrict__ flag) {
    const int i = blockIdx.x * 256 + threadIdx.x;
    if (i >= n) return;
    if (*flag) dst[i] = f2b(((const float*)src)[i]);
    else       dst[i] = ((const ushort*)src)[i];
}

__global__ __launch_bounds__(256) void cvt_f32(
    const void* __restrict__ src, float* __restrict__ dst, int n,
    const int* __restrict__ flag) {
    const int i = blockIdx.x * 256 + threadIdx.x;
    if (i >= n) return;
    if (*flag) dst[i] = ((const float*)src)[i];
    else       dst[i] = b2f(((const ushort*)src)[i]);
}

// ------------------------------------------------------------ padded features
// featPad[b][y][x][c], y:0..9, x:0..33 (1-halo, zero borders), bf16
__global__ __launch_bounds__(256) void build_featpad(
    const void* __restrict__ feat, ushort* __restrict__ featPad,
    const int* __restrict__ flag) {
    const int i = blockIdx.x * 256 + threadIdx.x;
    if (i >= 128 * 10 * 34 * 512) return;
    const int c = i & 511;
    const int xy = i >> 9;
    const int x = xy % 34;
    const int t2 = xy / 34;
    const int y = t2 % 10;
    const int b = t2 / 10;
    ushort v = 0;
    if (y >= 1 && y <= 8 && x >= 1 && x <= 32) {
        const size_t si = ((size_t)((b * 8 + y - 1) * 32 + (x - 1)) << 9) + c;
        v = *flag ? f2b(((const float*)feat)[si]) : ((const ushort*)feat)[si];
    }
    featPad[i] = v;
}

// ------------------------------------------------------------ transpose
__global__ __launch_bounds__(256) void transpose_any(
    const void* __restrict__ in, ushort* __restrict__ out, int R, int C,
    const int* __restrict__ flag) {
    __shared__ float s[32][33];
    const int f32 = *flag;
    const int nbc = C >> 5;
    const int rb = blockIdx.x / nbc, cb = blockIdx.x % nbc;
    const int tx = threadIdx.x & 31, ty = threadIdx.x >> 5;
#pragma unroll
    for (int k = 0; k < 4; ++k) {
        const size_t idx = (size_t)(rb * 32 + ty + k * 8) * C + cb * 32 + tx;
        s[ty + k * 8][tx] = f32 ? ((const float*)in)[idx] : b2f(((const ushort*)in)[idx]);
    }
    __syncthreads();
#pragma unroll
    for (int k = 0; k < 4; ++k)
        out[(size_t)(cb * 32 + ty + k * 8) * R + rb * 32 + tx] = f2b(s[tx][ty + k * 8]);
}

// ------------------------------------------------------------ outW^T pad
__global__ __launch_bounds__(256) void woT_build(
    const float* __restrict__ outWf, ushort* __restrict__ WoTpad) {
    const int i = blockIdx.x * 256 + threadIdx.x;
    if (i >= 131072) return;
    const int v = i >> 10, k = i & 1023;
    WoTpad[i] = (v < 111) ? f2b(outWf[k * 111 + v]) : (ushort)0;
}

// ------------------------------------------------------------ conv fproj
// M=32768 rows (b*256+p), N=512, K=9*512 tap-major. A from featPad (haloed),
// B=WfT[a][tap*512+c]. Staging via global_load_lds with XOR-swizzled LDS
// (slot chunk cs holds gmem chunk cs ^ (row&7)); ds_read_b128 stays 2-way.
__global__ __launch_bounds__(256) void conv_fproj(
    const ushort* __restrict__ featPad, const ushort* __restrict__ WfT,
    const float* __restrict__ bff, ushort* __restrict__ fproj) {
    __shared__ __align__(16) ushort As[128 * 64];
    __shared__ __align__(16) ushort Bs[128 * 64];
    const int tid = threadIdx.x;
    const int nb = blockIdx.x >> 8;          // 4 col-blocks (outer) -> XCD reuse of A
    const int rb = blockIdx.x & 255;         // 256 row-blocks
    const int b = rb >> 1, p0 = (rb & 1) << 7;
    const int w = tid >> 6, lane = tid & 63, l15 = lane & 15, q = lane >> 4;
    const int wr = (w >> 1) << 6, wc = (w & 1) << 6;
    // staging: wave w stages rows w*32+i*8+(lane>>3), slot chunk lane&7
    const int chunkoff = (((lane & 7) ^ (lane >> 3)) << 3);   // swizzled gmem chunk
    int aoff[4], boff[4];
#pragma unroll
    for (int i = 0; i < 4; ++i) {
        const int r = w * 32 + (lane >> 3) + i * 8;
        const int p = p0 + r;
        const int yy = p >> 5, xx = p & 31;
        aoff[i] = (((b * 10 + yy) * 34 + xx) << 9) + chunkoff;       // tap(0,0) base
        boff[i] = (nb * 128 + r) * 4608 + chunkoff;
    }
    const int swa = l15 & 7;                 // frag-read swizzle term
    f32x4 acc[4][4] = {};
    for (int kb = 0; kb < 72; ++kb) {
        const int tap = kb >> 3;
        const int dy = tap / 3, dx = tap - dy * 3;
        const int koffA = ((dy * 34 + dx) << 9) + ((kb & 7) << 6);
        const int koffB = kb * 64;
        __syncthreads();
#pragma unroll
        for (int i = 0; i < 4; ++i) {
            gl16(featPad + aoff[i] + koffA, &As[(w * 32 + i * 8) * 64]);
            gl16(WfT + boff[i] + koffB, &Bs[(w * 32 + i * 8) * 64]);
        }
        __syncthreads();
#pragma unroll
        for (int ks = 0; ks < 64; ks += 32) {
            const int cq = (ks >> 3) + q;
            const int col = ((cq ^ swa) << 3);
            bf16x8 af[4], bfr[4];
#pragma unroll
            for (int i = 0; i < 4; ++i) af[i] = *(const bf16x8*)&As[(wr + i * 16 + l15) * 64 + col];
#pragma unroll
            for (int j = 0; j < 4; ++j) bfr[j] = *(const bf16x8*)&Bs[(wc + j * 16 + l15) * 64 + col];
#pragma unroll
            for (int i = 0; i < 4; ++i)
#pragma unroll
                for (int j = 0; j < 4; ++j)
                    acc[i][j] = MFMA16(af[i], bfr[j], acc[i][j]);
        }
    }
    const int rowbase = rb * 128 + wr, colbase = nb * 128 + wc;
#pragma unroll
    for (int i = 0; i < 4; ++i)
#pragma unroll
        for (int j = 0; j < 4; ++j)
#pragma unroll
            for (int rr = 0; rr < 4; ++rr) {
                const int row = rowbase + i * 16 + q * 4 + rr;
                const int col = colbase + j * 16 + l15;
                fproj[(size_t)row * 512 + col] = f2b(acc[i][j][rr] + bff[col]);
            }
}

// ------------------------------------------------------------ generic GEMM
__global__ __launch_bounds__(256) void gemm_bt(
    const ushort* __restrict__ A, const ushort* __restrict__ BT,
    float* __restrict__ C, int M, int N, int K, int lda) {
    __shared__ __align__(16) bf16 As[128][72];
    __shared__ __align__(16) bf16 Bs[128][72];
    const int tid = threadIdx.x;
    const int nnb = N >> 7;
    const int rb = blockIdx.x / nnb, nb = blockIdx.x % nnb;
    const int ar = tid >> 1, ah = (tid & 1) << 5;
    const int w = tid >> 6, lane = tid & 63, l15 = lane & 15, q = lane >> 4;
    const int wr = (w >> 1) << 6, wc = (w & 1) << 6;
    const int r_glob = rb * 128 + ar;
    const bool aval = (r_glob < M);
    const int r_ld = aval ? r_glob : 0;
    f32x4 acc[4][4] = {};
    const int nkb = K >> 6;
    for (int kb = 0; kb < nkb; ++kb) {
        const uint4 z4 = {0u, 0u, 0u, 0u};
        const uint4* asrc = (const uint4*)(A + (size_t)r_ld * lda + kb * 64 + ah);
        uint4 a0 = asrc[0], a1 = asrc[1], a2 = asrc[2], a3 = asrc[3];
        if (!aval) { a0 = z4; a1 = z4; a2 = z4; a3 = z4; }
        const uint4* bsrc = (const uint4*)(BT + (size_t)(nb * 128 + ar) * K + kb * 64 + ah);
        uint4 b0v = bsrc[0], b1v = bsrc[1], b2v = bsrc[2], b3v = bsrc[3];
        __syncthreads();
        *(uint4*)&As[ar][ah] = a0;
        *(uint4*)&As[ar][ah + 8] = a1;
        *(uint4*)&As[ar][ah + 16] = a2;
        *(uint4*)&As[ar][ah + 24] = a3;
        *(uint4*)&Bs[ar][ah] = b0v;
        *(uint4*)&Bs[ar][ah + 8] = b1v;
        *(uint4*)&Bs[ar][ah + 16] = b2v;
        *(uint4*)&Bs[ar][ah + 24] = b3v;
        __syncthreads();
#pragma unroll
        for (int ks = 0; ks < 64; ks += 32) {
            bf16x8 af[4], bfr[4];
#pragma unroll
            for (int i = 0; i < 4; ++i) af[i] = *(const bf16x8*)&As[wr + i * 16 + l15][ks + q * 8];
#pragma unroll
            for (int j = 0; j < 4; ++j) bfr[j] = *(const bf16x8*)&Bs[wc + j * 16 + l15][ks + q * 8];
#pragma unroll
            for (int i = 0; i < 4; ++i)
#pragma unroll
                for (int j = 0; j < 4; ++j)
                    acc[i][j] = MFMA16(af[i], bfr[j], acc[i][j]);
        }
    }
#pragma unroll
    for (int i = 0; i < 4; ++i)
#pragma unroll
        for (int j = 0; j < 4; ++j)
#pragma unroll
            for (int rr = 0; rr < 4; ++rr) {
                const int row = rb * 128 + wr + i * 16 + q * 4 + rr;
                const int col = nb * 128 + wc + j * 16 + l15;
                if (row < M) C[(size_t)row * N + col] = acc[i][j][rr];
            }
}

// ------------------------------------------------------------ persistent LSTM
// 128 blocks: 0..63 = stage0 of step t, 64..127 = stage1 of step t-1.
// One cooperative launch; grid.sync() between the 34 steps.
__global__ __launch_bounds__(256) void lstm_persistent(
    const ushort* __restrict__ holistic, const int* __restrict__ gt,
    const float* __restrict__ b0f, const float* __restrict__ b1f,
    const ushort* __restrict__ k0T, const ushort* __restrict__ rk0T,
    const ushort* __restrict__ k1T, const ushort* __restrict__ rk1T,
    const float* __restrict__ E0,
    ushort* h0b0, ushort* h0b1, ushort* h1b0, ushort* h1b1,
    float* c0buf, float* c1buf, ushort* HG) {
    cg::grid_group gg = cg::this_grid();
    const int part = blockIdx.x >> 6;
    const int bi = blockIdx.x & 63;
    const int m0 = (bi >> 4) << 5;
    const int cc0 = (bi & 15) << 5;
    const int tid = threadIdx.x;
    const int w = tid >> 6, lane = tid & 63, l15 = lane & 15, q = lane >> 4;
    __shared__ __align__(16) bf16 As[32][72];
    __shared__ __align__(16) bf16 Bs[4][32][72];
    __shared__ float zs[4][32][33];
    const int arr = tid >> 3, aco = (tid & 7) << 3;
    const int bn = lane >> 1, bho = (lane & 1) << 5;
    for (int t = -2; t <= 31; ++t) {
        const ushort *A1 = nullptr, *A2 = nullptr, *B1 = nullptr, *B2 = nullptr;
        const float* bias = nullptr;
        ushort *hout = nullptr, *hout2 = nullptr;
        float* cbuf = nullptr;
        bool useC = false, useE = false, active = false;
        int nkb = 8;
        if (part == 0) {
            if (t == -2 || (t >= 0 && t <= 30)) {
                active = true; bias = b0f; cbuf = c0buf;
                if (t == -2) { A1 = holistic; B1 = k0T; hout = h0b1; }
                else {
                    A1 = ((t + 1) & 1) ? h0b1 : h0b0;
                    B1 = rk0T;
                    hout = (t & 1) ? h0b1 : h0b0;
                    useC = true; useE = true;
                }
            }
        } else {
            if (t == -1 || (t >= 1 && t <= 31)) {
                active = true; bias = b1f; cbuf = c1buf;
                if (t == -1) { A1 = h0b1; B1 = k1T; hout = h1b1; }
                else {
                    const int s = t - 1;
                    A1 = (s & 1) ? h0b1 : h0b0;           // h0 of step s
                    A2 = ((s + 1) & 1) ? h1b1 : h1b0;     // h1 of step s-1
                    B1 = k1T; B2 = rk1T;
                    hout = (s & 1) ? h1b1 : h1b0;
                    hout2 = HG + (size_t)s * 131072;      // row stride 1024
                    useC = true; nkb = 16;
                }
            }
        }
        if (active) {
            f32x4 acc[2][2] = {};
            for (int kb = 0; kb < nkb; ++kb) {
                const ushort* ap = (kb < 8) ? (A1 + (size_t)(m0 + arr) * 512 + kb * 64 + aco)
                                            : (A2 + (size_t)(m0 + arr) * 512 + (kb - 8) * 64 + aco);
                uint4 av = *(const uint4*)ap;
                const ushort* bp = (kb < 8) ? (B1 + (size_t)(w * 512 + cc0 + bn) * 512 + kb * 64 + bho)
                                            : (B2 + (size_t)(w * 512 + cc0 + bn) * 512 + (kb - 8) * 64 + bho);
                uint4 bv0 = ((const uint4*)bp)[0];
                uint4 bv1 = ((const uint4*)bp)[1];
                uint4 bv2 = ((const uint4*)bp)[2];
                uint4 bv3 = ((const uint4*)bp)[3];
                __syncthreads();
                *(uint4*)&As[arr][aco] = av;
                *(uint4*)&Bs[w][bn][bho] = bv0;
                *(uint4*)&Bs[w][bn][bho + 8] = bv1;
                *(uint4*)&Bs[w][bn][bho + 16] = bv2;
                *(uint4*)&Bs[w][bn][bho + 24] = bv3;
                __syncthreads();
#pragma unroll
                for (int ks = 0; ks < 64; ks += 32) {
                    bf16x8 af0 = *(const bf16x8*)&As[l15][ks + q * 8];
                    bf16x8 af1 = *(const bf16x8*)&As[16 + l15][ks + q * 8];
                    bf16x8 bf0 = *(const bf16x8*)&Bs[w][l15][ks + q * 8];
                    bf16x8 bf1 = *(const bf16x8*)&Bs[w][16 + l15][ks + q * 8];
                    acc[0][0] = MFMA16(af0, bf0, acc[0][0]);
                    acc[0][1] = MFMA16(af0, bf1, acc[0][1]);
                    acc[1][0] = MFMA16(af1, bf0, acc[1][0]);
                    acc[1][1] = MFMA16(af1, bf1, acc[1][1]);
                }
            }
            __syncthreads();
#pragma unroll
            for (int i = 0; i < 2; ++i)
#pragma unroll
                for (int j = 0; j < 2; ++j)
#pragma unroll
                    for (int rr = 0; rr < 4; ++rr)
                        zs[w][i * 16 + q * 4 + rr][j * 16 + l15] = acc[i][j][rr];
            __syncthreads();
            for (int e = tid; e < 1024; e += 256) {
                const int mm = e >> 5, cc = e & 31;
                const int brow = m0 + mm, col = cc0 + cc;
                float zi = zs[0][mm][cc] + bias[col];
                float zf = zs[1][mm][cc] + bias[512 + col];
                float zg = zs[2][mm][cc] + bias[1024 + col];
                float zo = zs[3][mm][cc] + bias[1536 + col];
                if (useE) {
                    const int s = (t == 0) ? 111 : gt[brow * 31 + t - 1];
                    if (s >= 0 && s < 111) {
                        const float* er = E0 + (size_t)s * 2048;
                        zi += er[col]; zf += er[512 + col]; zg += er[1024 + col]; zo += er[1536 + col];
                    }
                }
                const float cp = useC ? cbuf[brow * 512 + col] : 0.0f;
                const float c2 = sig_fast(zf) * cp + sig_fast(zi) * tanh_fast(zg);
                const float h = sig_fast(zo) * tanh_fast(c2);
                cbuf[brow * 512 + col] = c2;
                hout[brow * 512 + col] = f2b(h);
                if (hout2) hout2[brow * 1024 + col] = f2b(h);
            }
        }
        gg.sync();
    }
}

// ------------------------------------------------------------ attention logits
__global__ __launch_bounds__(256) void att_logits(
    const ushort* __restrict__ fproj, const float* __restrict__ HP,
    const float* __restrict__ waf, float* __restrict__ attL) {
    __shared__ float hpS[31][512];
    __shared__ float waS[512];
    __shared__ float accS[128][33];
    const int tid = threadIdx.x;
    const int b = blockIdx.x >> 1, ph = blockIdx.x & 1;
    const int pl = tid & 127, ch = tid >> 7;
    const int p = ph * 128 + pl;
    for (int i = tid; i < 31 * 512; i += 256) {
        const int tt = i >> 9, c = i & 511;
        hpS[tt][c] = HP[((size_t)tt * 128 + b) * 512 + c];
    }
    waS[tid] = waf[tid];
    if (tid < 256) waS[256 + tid] = waf[256 + tid];
    __syncthreads();
    float acc[31];
#pragma unroll
    for (int tt = 0; tt < 31; ++tt) acc[tt] = 0.f;
    const ushort* frow = fproj + (size_t)(b * 256 + p) * 512 + ch * 256;
    for (int c8 = 0; c8 < 32; ++c8) {
        const int cc = ch * 256 + c8 * 8;
        const uint4 fv = *(const uint4*)(frow + c8 * 8);
        float f[8];
        f[0] = b2f((unsigned short)(fv.x & 0xffff)); f[1] = b2f((unsigned short)(fv.x >> 16));
        f[2] = b2f((unsigned short)(fv.y & 0xffff)); f[3] = b2f((unsigned short)(fv.y >> 16));
        f[4] = b2f((unsigned short)(fv.z & 0xffff)); f[5] = b2f((unsigned short)(fv.z >> 16));
        f[6] = b2f((unsigned short)(fv.w & 0xffff)); f[7] = b2f((unsigned short)(fv.w >> 16));
        float w8[8];
#pragma unroll
        for (int j = 0; j < 8; ++j) w8[j] = waS[cc + j];
#pragma unroll
        for (int tt = 0; tt < 31; ++tt) {
            const float* hp8 = &hpS[tt][cc];   // wave-uniform -> broadcast
            float s = 0.f;
#pragma unroll
            for (int j = 0; j < 8; ++j)
                s += tanh_fast(f[j] + hp8[j]) * w8[j];
            acc[tt] += s;
        }
    }
    if (ch == 1) {
#pragma unroll
        for (int tt = 0; tt < 31; ++tt) accS[pl][tt] = acc[tt];
    }
    __syncthreads();
    if (ch == 0) {
#pragma unroll
        for (int tt = 0; tt < 31; ++tt)
            attL[((size_t)tt * 128 + b) * 256 + p] = acc[tt] + accS[pl][tt];
    }
}

// ------------------------------------------------------------ glimpse (+softmax)
__global__ __launch_bounds__(256) void glimpse_kernel(
    const ushort* __restrict__ featPad, const float* __restrict__ attL,
    ushort* __restrict__ HG) {
    __shared__ float attS[31][256];
    const int tid = threadIdx.x;
    const int b = blockIdx.x >> 1, chh = blockIdx.x & 1;
    const int c0 = chh << 8;
    const int w = tid >> 6, lane = tid & 63;
    for (int i = tid; i < 31 * 256; i += 256) {
        const int tt = i >> 8, p = i & 255;
        attS[tt][p] = attL[((size_t)tt * 128 + b) * 256 + p];
    }
    __syncthreads();
    for (int tt = w; tt < 31; tt += 4) {
        float v0 = attS[tt][lane], v1 = attS[tt][lane + 64];
        float v2 = attS[tt][lane + 128], v3 = attS[tt][lane + 192];
        float mx = fmaxf(fmaxf(v0, v1), fmaxf(v2, v3));
#pragma unroll
        for (int m = 1; m < 64; m <<= 1) mx = fmaxf(mx, __shfl_xor(mx, m));
        const float e0 = expf(v0 - mx), e1 = expf(v1 - mx);
        const float e2 = expf(v2 - mx), e3 = expf(v3 - mx);
        float s = e0 + e1 + e2 + e3;
#pragma unroll
        for (int m = 1; m < 64; m <<= 1) s += __shfl_xor(s, m);
        const float r = 1.0f / s;
        attS[tt][lane] = e0 * r;  attS[tt][lane + 64] = e1 * r;
        attS[tt][lane + 128] = e2 * r;  attS[tt][lane + 192] = e3 * r;
    }
    __syncthreads();
    float acc[31];
#pragma unroll
    for (int tt = 0; tt < 31; ++tt) acc[tt] = 0.f;
    for (int p = 0; p < 256; ++p) {
        const size_t fi = (((size_t)(b * 10 + (p >> 5) + 1) * 34 + (p & 31) + 1) << 9) + c0 + tid;
        const float fv = b2f(featPad[fi]);
#pragma unroll
        for (int tt = 0; tt < 31; ++tt) acc[tt] += fv * attS[tt][p];
    }
#pragma unroll
    for (int tt = 0; tt < 31; ++tt)
        HG[((size_t)tt * 128 + b) * 1024 + 512 + c0 + tid] = f2b(acc[tt]);
}

// ------------------------------------------------------------ logits store
__global__ __launch_bounds__(256) void logits_store(
    const float* __restrict__ C, const float* __restrict__ outBf,
    void* __restrict__ out, const int* __restrict__ flag) {
    const int i = blockIdx.x * 256 + threadIdx.x;
    if (i >= 3968 * 111) return;
    const int r = i / 111, v = i - r * 111;
    const int tt = r >> 7, b = r & 127;
    const float a = C[(size_t)r * 128 + v] + outBf[v];
    const size_t oi = ((size_t)b * 31 + tt) * 111 + v;
    if (*flag) ((float*)out)[oi] = a;
    else       ((ushort*)out)[oi] = f2b(a);
}

// ------------------------------------------------------------ launch
extern "C" void kernel_launch(void* const* d_in, const int* in_sizes, int n_in,
                              void* d_out, int out_size, void* d_ws, size_t ws_size,
                              hipStream_t stream) {
    (void)in_sizes; (void)n_in; (void)out_size;
    const void* features = d_in[0];
    const void* holistic = d_in[1];
    const int*  gt       = (const int*)d_in[2];
    const void* embed_W  = d_in[3];
    const void* k0 = d_in[4];
    const void* rk0 = d_in[5];
    const void* b0 = d_in[6];
    const void* k1 = d_in[7];
    const void* rk1 = d_in[8];
    const void* b1 = d_in[9];
    const void* Wh = d_in[10];
    const void* Wf = d_in[11];
    const void* bfv = d_in[12];
    const void* wa = d_in[13];
    const void* outW = d_in[14];
    const void* outB = d_in[15];

    char* ws = (char*)d_ws;
    size_t off = 0;
    auto take = [&](size_t bytes) -> char* {
        char* p = ws + off;
        off += (bytes + 255) & ~(size_t)255;
        return p;
    };
    int*    flag    = (int*)take(256);
    ushort* featPad = (ushort*)take(128ull * 10 * 34 * 512 * 2);   // 44.6 MB
    ushort* holB  = (ushort*)take(65536ull * 2);
    ushort* embB  = (ushort*)take(56832ull * 2);
    float*  b0f   = (float*)take(2048ull * 4);
    float*  b1f   = (float*)take(2048ull * 4);
    float*  bff   = (float*)take(512ull * 4);
    float*  waf   = (float*)take(512ull * 4);
    float*  outBf = (float*)take(111ull * 4);
    float*  outWf = (float*)take(113664ull * 4);
    ushort* fproj = (ushort*)take(32768ull * 512 * 2);             // 33.5 MB
    ushort* WfT   = (ushort*)take(4608ull * 512 * 2);
    ushort* k0T   = (ushort*)take(2048ull * 512 * 2);
    ushort* rk0T  = (ushort*)take(2048ull * 512 * 2);
    ushort* k1T   = (ushort*)take(2048ull * 512 * 2);
    ushort* rk1T  = (ushort*)take(2048ull * 512 * 2);
    ushort* WhT   = (ushort*)take(512ull * 512 * 2);
    float*  E0    = (float*)take(111ull * 2048 * 4);
    ushort* h0b0  = (ushort*)take(128ull * 512 * 2);
    ushort* h0b1  = (ushort*)take(128ull * 512 * 2);
    ushort* h1b0  = (ushort*)take(128ull * 512 * 2);
    ushort* h1b1  = (ushort*)take(128ull * 512 * 2);
    float*  c0buf = (float*)take(128ull * 512 * 4);
    float*  c1buf = (float*)take(128ull * 512 * 4);
    ushort* HG    = (ushort*)take(3968ull * 1024 * 2);             // [H1 | glimpse]
    float*  HP    = (float*)take(3968ull * 512 * 4);
    float*  attL  = (float*)take(31ull * 128 * 256 * 4);
    float*  Cout   = (float*)attL;                                  // alias (stream-serial)
    ushort* WoTpad = (ushort*)((char*)attL + 3968ull * 128 * 4);
    if (off > ws_size) return;

    // 0) dtype detect + canonicalize
    detect_dtype<<<dim3(1), dim3(64), 0, stream>>>(features, flag);
    build_featpad<<<dim3(87040), dim3(256), 0, stream>>>(features, featPad, flag);
    cvt_bf16<<<dim3(256), dim3(256), 0, stream>>>(holistic, holB, 65536, flag);
    cvt_bf16<<<dim3(222), dim3(256), 0, stream>>>(embed_W, embB, 56832, flag);
    cvt_f32<<<dim3(8), dim3(256), 0, stream>>>(b0, b0f, 2048, flag);
    cvt_f32<<<dim3(8), dim3(256), 0, stream>>>(b1, b1f, 2048, flag);
    cvt_f32<<<dim3(2), dim3(256), 0, stream>>>(bfv, bff, 512, flag);
    cvt_f32<<<dim3(2), dim3(256), 0, stream>>>(wa, waf, 512, flag);
    cvt_f32<<<dim3(1), dim3(256), 0, stream>>>(outB, outBf, 111, flag);
    cvt_f32<<<dim3(444), dim3(256), 0, stream>>>(outW, outWf, 113664, flag);
    // 1) weight transposes
    transpose_any<<<dim3(16 * 64), dim3(256), 0, stream>>>(k0, k0T, 512, 2048, flag);
    transpose_any<<<dim3(16 * 64), dim3(256), 0, stream>>>(rk0, rk0T, 512, 2048, flag);
    transpose_any<<<dim3(16 * 64), dim3(256), 0, stream>>>(k1, k1T, 512, 2048, flag);
    transpose_any<<<dim3(16 * 64), dim3(256), 0, stream>>>(rk1, rk1T, 512, 2048, flag);
    transpose_any<<<dim3(16 * 16), dim3(256), 0, stream>>>(Wh, WhT, 512, 512, flag);
    transpose_any<<<dim3(144 * 16), dim3(256), 0, stream>>>(Wf, WfT, 4608, 512, flag);
    // 2) conv fproj
    conv_fproj<<<dim3(1024), dim3(256), 0, stream>>>(featPad, WfT, bff, fproj);
    // 3) E0 = embed_W @ k0
    gemm_bt<<<dim3(16), dim3(256), 0, stream>>>(embB, k0T, E0, 111, 2048, 512, 512);
    // 4) recurrence: one persistent cooperative kernel
    {
        void* kargs[] = {
            (void*)&holB, (void*)&gt, (void*)&b0f, (void*)&b1f,
            (void*)&k0T, (void*)&rk0T, (void*)&k1T, (void*)&rk1T,
            (void*)&E0, (void*)&h0b0, (void*)&h0b1, (void*)&h1b0, (void*)&h1b1,
            (void*)&c0buf, (void*)&c1buf, (void*)&HG
        };
        hipLaunchCooperativeKernel((void*)lstm_persistent, dim3(128), dim3(256),
                                   kargs, 0, stream);
    }
    // 5) batched epilogue
    gemm_bt<<<dim3(31 * 4), dim3(256), 0, stream>>>(HG, WhT, HP, 3968, 512, 512, 1024);
    att_logits<<<dim3(256), dim3(256), 0, stream>>>(fproj, HP, waf, attL);
    glimpse_kernel<<<dim3(256), dim3(256), 0, stream>>>(featPad, attL, HG);
    woT_build<<<dim3(512), dim3(256), 0, stream>>>(outWf, WoTpad);
    gemm_bt<<<dim3(31), dim3(256), 0, stream>>>(HG, WoTpad, Cout, 3968, 128, 1024, 1024);
    logits_store<<<dim3(1721), dim3(256), 0, stream>>>(Cout, outBf, d_out, flag);
}

// Round 5
// 1388.440 us; speedup vs baseline: 1.2644x; 1.2644x over previous
//
#include <hip/hip_runtime.h>

// SARDecoder on MI355X (gfx950). Dtype-robust (runtime bf16-vs-fp32 detect).
//
// Round-5 changes:
//  - recurrence back to 34 per-step dispatches (cooperative grid.sync measured
//    at ~28us/step -> removed)
//  - lstm_stage: A/B MFMA fragments loaded DIRECTLY from global (L2-hot,
//    64B-contiguous per 16 rows), no LDS staging, no k-loop barriers
//  - conv_fproj keeps global_load_lds(16B) + XOR-swizzled LDS (round-4 win)

typedef __bf16 bf16;
typedef bf16 bf16x8 __attribute__((ext_vector_type(8)));
typedef float f32x4 __attribute__((ext_vector_type(4)));

#define MFMA16(a, b, c) __builtin_amdgcn_mfma_f32_16x16x32_bf16((a), (b), (c), 0, 0, 0)

__device__ __forceinline__ float b2f(unsigned short u) {
    return __uint_as_float(((unsigned int)u) << 16);
}
__device__ __forceinline__ unsigned short f2b(float f) {
    unsigned int x = __float_as_uint(f);
    unsigned int r = (x + 0x7fffu + ((x >> 16) & 1u)) >> 16;   // RNE
    return (unsigned short)r;
}
__device__ __forceinline__ float tanh_fast(float x) {
    const float e = exp2f(2.885390082f * x);                   // 2/ln2
    return 1.0f - 2.0f * __builtin_amdgcn_rcpf(e + 1.0f);
}
__device__ __forceinline__ float sig_fast(float x) {
    return __builtin_amdgcn_rcpf(1.0f + exp2f(-1.44269504f * x));
}
// async 16B/lane global->LDS. lds dest is wave-uniform base + lane*16.
__device__ __forceinline__ void gl16(const ushort* g, ushort* l) {
    __builtin_amdgcn_global_load_lds(
        (const __attribute__((address_space(1))) void*)g,
        (__attribute__((address_space(3))) void*)l, 16, 0, 0);
}

// ------------------------------------------------------------ dtype detect
__global__ void detect_dtype(const void* __restrict__ feat, int* __restrict__ flag) {
    if (threadIdx.x == 0 && blockIdx.x == 0) {
        const ushort* u = (const ushort*)feat;
        int cnt = 0;
        for (int i = 0; i < 128; i += 2) {
            const int e = (u[i] >> 7) & 0xFF;
            if (e >= 96 && e <= 150) ++cnt;
        }
        *flag = (cnt >= 40) ? 0 : 1;
    }
}

// ------------------------------------------------------------ converters
__global__ __launch_bounds__(256) void cvt_bf16(
    const void* __restrict__ src, ushort* __restrict__ dst, int n,
    const int* __restrict__ flag) {
    const int i = blockIdx.x * 256 + threadIdx.x;
    if (i >= n) return;
    if (*flag) dst[i] = f2b(((const float*)src)[i]);
    else       dst[i] = ((const ushort*)src)[i];
}

__global__ __launch_bounds__(256) void cvt_f32(
    const void* __restrict__ src, float* __restrict__ dst, int n,
    const int* __restrict__ flag) {
    const int i = blockIdx.x * 256 + threadIdx.x;
    if (i >= n) return;
    if (*flag) dst[i] = ((const float*)src)[i];
    else       dst[i] = b2f(((const ushort*)src)[i]);
}

// ------------------------------------------------------------ padded features
// featPad[b][y][x][c], y:0..9, x:0..33 (1-halo, zero borders), bf16
__global__ __launch_bounds__(256) void build_featpad(
    const void* __restrict__ feat, ushort* __restrict__ featPad,
    const int* __restrict__ flag) {
    const int i = blockIdx.x * 256 + threadIdx.x;
    if (i >= 128 * 10 * 34 * 512) return;
    const int c = i & 511;
    const int xy = i >> 9;
    const int x = xy % 34;
    const int t2 = xy / 34;
    const int y = t2 % 10;
    const int b = t2 / 10;
    ushort v = 0;
    if (y >= 1 && y <= 8 && x >= 1 && x <= 32) {
        const size_t si = ((size_t)((b * 8 + y - 1) * 32 + (x - 1)) << 9) + c;
        v = *flag ? f2b(((const float*)feat)[si]) : ((const ushort*)feat)[si];
    }
    featPad[i] = v;
}

// ------------------------------------------------------------ transpose
__global__ __launch_bounds__(256) void transpose_any(
    const void* __restrict__ in, ushort* __restrict__ out, int R, int C,
    const int* __restrict__ flag) {
    __shared__ float s[32][33];
    const int f32 = *flag;
    const int nbc = C >> 5;
    const int rb = blockIdx.x / nbc, cb = blockIdx.x % nbc;
    const int tx = threadIdx.x & 31, ty = threadIdx.x >> 5;
#pragma unroll
    for (int k = 0; k < 4; ++k) {
        const size_t idx = (size_t)(rb * 32 + ty + k * 8) * C + cb * 32 + tx;
        s[ty + k * 8][tx] = f32 ? ((const float*)in)[idx] : b2f(((const ushort*)in)[idx]);
    }
    __syncthreads();
#pragma unroll
    for (int k = 0; k < 4; ++k)
        out[(size_t)(cb * 32 + ty + k * 8) * R + rb * 32 + tx] = f2b(s[tx][ty + k * 8]);
}

// ------------------------------------------------------------ outW^T pad
__global__ __launch_bounds__(256) void woT_build(
    const float* __restrict__ outWf, ushort* __restrict__ WoTpad) {
    const int i = blockIdx.x * 256 + threadIdx.x;
    if (i >= 131072) return;
    const int v = i >> 10, k = i & 1023;
    WoTpad[i] = (v < 111) ? f2b(outWf[k * 111 + v]) : (ushort)0;
}

// ------------------------------------------------------------ conv fproj
// M=32768 rows (b*256+p), N=512, K=9*512 tap-major. A from featPad (haloed),
// B=WfT[a][tap*512+c]. Staging via global_load_lds with XOR-swizzled LDS.
__global__ __launch_bounds__(256) void conv_fproj(
    const ushort* __restrict__ featPad, const ushort* __restrict__ WfT,
    const float* __restrict__ bff, ushort* __restrict__ fproj) {
    __shared__ __align__(16) ushort As[128 * 64];
    __shared__ __align__(16) ushort Bs[128 * 64];
    const int tid = threadIdx.x;
    const int nb = blockIdx.x >> 8;          // 4 col-blocks (outer)
    const int rb = blockIdx.x & 255;         // 256 row-blocks
    const int b = rb >> 1, p0 = (rb & 1) << 7;
    const int w = tid >> 6, lane = tid & 63, l15 = lane & 15, q = lane >> 4;
    const int wr = (w >> 1) << 6, wc = (w & 1) << 6;
    const int chunkoff = (((lane & 7) ^ (lane >> 3)) << 3);   // swizzled gmem chunk
    int aoff[4], boff[4];
#pragma unroll
    for (int i = 0; i < 4; ++i) {
        const int r = w * 32 + (lane >> 3) + i * 8;
        const int p = p0 + r;
        const int yy = p >> 5, xx = p & 31;
        aoff[i] = (((b * 10 + yy) * 34 + xx) << 9) + chunkoff;
        boff[i] = (nb * 128 + r) * 4608 + chunkoff;
    }
    const int swa = l15 & 7;
    f32x4 acc[4][4] = {};
    for (int kb = 0; kb < 72; ++kb) {
        const int tap = kb >> 3;
        const int dy = tap / 3, dx = tap - dy * 3;
        const int koffA = ((dy * 34 + dx) << 9) + ((kb & 7) << 6);
        const int koffB = kb * 64;
        __syncthreads();
#pragma unroll
        for (int i = 0; i < 4; ++i) {
            gl16(featPad + aoff[i] + koffA, &As[(w * 32 + i * 8) * 64]);
            gl16(WfT + boff[i] + koffB, &Bs[(w * 32 + i * 8) * 64]);
        }
        __syncthreads();
#pragma unroll
        for (int ks = 0; ks < 64; ks += 32) {
            const int cq = (ks >> 3) + q;
            const int col = ((cq ^ swa) << 3);
            bf16x8 af[4], bfr[4];
#pragma unroll
            for (int i = 0; i < 4; ++i) af[i] = *(const bf16x8*)&As[(wr + i * 16 + l15) * 64 + col];
#pragma unroll
            for (int j = 0; j < 4; ++j) bfr[j] = *(const bf16x8*)&Bs[(wc + j * 16 + l15) * 64 + col];
#pragma unroll
            for (int i = 0; i < 4; ++i)
#pragma unroll
                for (int j = 0; j < 4; ++j)
                    acc[i][j] = MFMA16(af[i], bfr[j], acc[i][j]);
        }
    }
    const int rowbase = rb * 128 + wr, colbase = nb * 128 + wc;
#pragma unroll
    for (int i = 0; i < 4; ++i)
#pragma unroll
        for (int j = 0; j < 4; ++j)
#pragma unroll
            for (int rr = 0; rr < 4; ++rr) {
                const int row = rowbase + i * 16 + q * 4 + rr;
                const int col = colbase + j * 16 + l15;
                fproj[(size_t)row * 512 + col] = f2b(acc[i][j][rr] + bff[col]);
            }
}

// ------------------------------------------------------------ generic GEMM
__global__ __launch_bounds__(256) void gemm_bt(
    const ushort* __restrict__ A, const ushort* __restrict__ BT,
    float* __restrict__ C, int M, int N, int K, int lda) {
    __shared__ __align__(16) bf16 As[128][72];
    __shared__ __align__(16) bf16 Bs[128][72];
    const int tid = threadIdx.x;
    const int nnb = N >> 7;
    const int rb = blockIdx.x / nnb, nb = blockIdx.x % nnb;
    const int ar = tid >> 1, ah = (tid & 1) << 5;
    const int w = tid >> 6, lane = tid & 63, l15 = lane & 15, q = lane >> 4;
    const int wr = (w >> 1) << 6, wc = (w & 1) << 6;
    const int r_glob = rb * 128 + ar;
    const bool aval = (r_glob < M);
    const int r_ld = aval ? r_glob : 0;
    f32x4 acc[4][4] = {};
    const int nkb = K >> 6;
    for (int kb = 0; kb < nkb; ++kb) {
        const uint4 z4 = {0u, 0u, 0u, 0u};
        const uint4* asrc = (const uint4*)(A + (size_t)r_ld * lda + kb * 64 + ah);
        uint4 a0 = asrc[0], a1 = asrc[1], a2 = asrc[2], a3 = asrc[3];
        if (!aval) { a0 = z4; a1 = z4; a2 = z4; a3 = z4; }
        const uint4* bsrc = (const uint4*)(BT + (size_t)(nb * 128 + ar) * K + kb * 64 + ah);
        uint4 b0v = bsrc[0], b1v = bsrc[1], b2v = bsrc[2], b3v = bsrc[3];
        __syncthreads();
        *(uint4*)&As[ar][ah] = a0;
        *(uint4*)&As[ar][ah + 8] = a1;
        *(uint4*)&As[ar][ah + 16] = a2;
        *(uint4*)&As[ar][ah + 24] = a3;
        *(uint4*)&Bs[ar][ah] = b0v;
        *(uint4*)&Bs[ar][ah + 8] = b1v;
        *(uint4*)&Bs[ar][ah + 16] = b2v;
        *(uint4*)&Bs[ar][ah + 24] = b3v;
        __syncthreads();
#pragma unroll
        for (int ks = 0; ks < 64; ks += 32) {
            bf16x8 af[4], bfr[4];
#pragma unroll
            for (int i = 0; i < 4; ++i) af[i] = *(const bf16x8*)&As[wr + i * 16 + l15][ks + q * 8];
#pragma unroll
            for (int j = 0; j < 4; ++j) bfr[j] = *(const bf16x8*)&Bs[wc + j * 16 + l15][ks + q * 8];
#pragma unroll
            for (int i = 0; i < 4; ++i)
#pragma unroll
                for (int j = 0; j < 4; ++j)
                    acc[i][j] = MFMA16(af[i], bfr[j], acc[i][j]);
        }
    }
#pragma unroll
    for (int i = 0; i < 4; ++i)
#pragma unroll
        for (int j = 0; j < 4; ++j)
#pragma unroll
            for (int rr = 0; rr < 4; ++rr) {
                const int row = rb * 128 + wr + i * 16 + q * 4 + rr;
                const int col = nb * 128 + wc + j * 16 + l15;
                if (row < M) C[(size_t)row * N + col] = acc[i][j][rr];
            }
}

// ------------------------------------------------------------ LSTM stage
// blocks 0..63: stage0 of step t; blocks 64..127: stage1 of step t-1.
// A/B fragments straight from global (L2-hot; 64B-contiguous per 16 rows).
// No LDS staging, no k-loop barriers.
__global__ __launch_bounds__(256) void lstm_stage(
    int t,
    const ushort* __restrict__ holistic, const int* __restrict__ gt,
    const float* __restrict__ b0f, const float* __restrict__ b1f,
    const ushort* __restrict__ k0T, const ushort* __restrict__ rk0T,
    const ushort* __restrict__ k1T, const ushort* __restrict__ rk1T,
    const float* __restrict__ E0,
    ushort* h0b0, ushort* h0b1, ushort* h1b0, ushort* h1b1,
    float* c0buf, float* c1buf, ushort* HG) {
    const int part = blockIdx.x >> 6;
    const int bi = blockIdx.x & 63;
    const ushort *A1 = nullptr, *A2 = nullptr, *B1 = nullptr, *B2 = nullptr;
    const float* bias = nullptr;
    ushort *hout = nullptr, *hout2 = nullptr;
    float* cbuf = nullptr;
    bool useC = false, useE = false;
    if (part == 0) {
        if (!(t == -2 || (t >= 0 && t <= 30))) return;
        bias = b0f; cbuf = c0buf;
        if (t == -2) { A1 = holistic; B1 = k0T; hout = h0b1; }
        else {
            A1 = ((t + 1) & 1) ? h0b1 : h0b0;
            B1 = rk0T;
            hout = (t & 1) ? h0b1 : h0b0;
            useC = true; useE = true;
        }
    } else {
        if (!(t == -1 || (t >= 1 && t <= 31))) return;
        bias = b1f; cbuf = c1buf;
        if (t == -1) { A1 = h0b1; B1 = k1T; hout = h1b1; }
        else {
            const int s = t - 1;
            A1 = (s & 1) ? h0b1 : h0b0;           // h0 of step s
            A2 = ((s + 1) & 1) ? h1b1 : h1b0;     // h1 of step s-1
            B1 = k1T; B2 = rk1T;
            hout = (s & 1) ? h1b1 : h1b0;
            hout2 = HG + (size_t)s * 131072;      // row stride 1024
            useC = true;
        }
    }
    const int m0 = (bi >> 4) << 5;
    const int cc0 = (bi & 15) << 5;
    const int tid = threadIdx.x;
    const int w = tid >> 6, lane = tid & 63, l15 = lane & 15, q = lane >> 4;
    __shared__ float zs[4][32][33];
    f32x4 acc[2][2] = {};
    {
        const ushort* a0p = A1 + (size_t)(m0 + l15) * 512 + q * 8;
        const ushort* a1p = A1 + (size_t)(m0 + 16 + l15) * 512 + q * 8;
        const ushort* b0p = B1 + (size_t)(w * 512 + cc0 + l15) * 512 + q * 8;
        const ushort* b1p = B1 + (size_t)(w * 512 + cc0 + 16 + l15) * 512 + q * 8;
#pragma unroll 4
        for (int ks = 0; ks < 512; ks += 32) {
            bf16x8 af0 = *(const bf16x8*)(a0p + ks);
            bf16x8 af1 = *(const bf16x8*)(a1p + ks);
            bf16x8 bf0 = *(const bf16x8*)(b0p + ks);
            bf16x8 bf1 = *(const bf16x8*)(b1p + ks);
            acc[0][0] = MFMA16(af0, bf0, acc[0][0]);
            acc[0][1] = MFMA16(af0, bf1, acc[0][1]);
            acc[1][0] = MFMA16(af1, bf0, acc[1][0]);
            acc[1][1] = MFMA16(af1, bf1, acc[1][1]);
        }
    }
    if (A2) {
        const ushort* a0p = A2 + (size_t)(m0 + l15) * 512 + q * 8;
        const ushort* a1p = A2 + (size_t)(m0 + 16 + l15) * 512 + q * 8;
        const ushort* b0p = B2 + (size_t)(w * 512 + cc0 + l15) * 512 + q * 8;
        const ushort* b1p = B2 + (size_t)(w * 512 + cc0 + 16 + l15) * 512 + q * 8;
#pragma unroll 4
        for (int ks = 0; ks < 512; ks += 32) {
            bf16x8 af0 = *(const bf16x8*)(a0p + ks);
            bf16x8 af1 = *(const bf16x8*)(a1p + ks);
            bf16x8 bf0 = *(const bf16x8*)(b0p + ks);
            bf16x8 bf1 = *(const bf16x8*)(b1p + ks);
            acc[0][0] = MFMA16(af0, bf0, acc[0][0]);
            acc[0][1] = MFMA16(af0, bf1, acc[0][1]);
            acc[1][0] = MFMA16(af1, bf0, acc[1][0]);
            acc[1][1] = MFMA16(af1, bf1, acc[1][1]);
        }
    }
#pragma unroll
    for (int i = 0; i < 2; ++i)
#pragma unroll
        for (int j = 0; j < 2; ++j)
#pragma unroll
            for (int rr = 0; rr < 4; ++rr)
                zs[w][i * 16 + q * 4 + rr][j * 16 + l15] = acc[i][j][rr];
    __syncthreads();
    for (int e = tid; e < 1024; e += 256) {
        const int mm = e >> 5, cc = e & 31;
        const int brow = m0 + mm, col = cc0 + cc;
        float zi = zs[0][mm][cc] + bias[col];
        float zf = zs[1][mm][cc] + bias[512 + col];
        float zg = zs[2][mm][cc] + bias[1024 + col];
        float zo = zs[3][mm][cc] + bias[1536 + col];
        if (useE) {
            const int s = (t == 0) ? 111 : gt[brow * 31 + t - 1];
            if (s >= 0 && s < 111) {
                const float* er = E0 + (size_t)s * 2048;
                zi += er[col]; zf += er[512 + col]; zg += er[1024 + col]; zo += er[1536 + col];
            }
        }
        const float cp = useC ? cbuf[brow * 512 + col] : 0.0f;
        const float c2 = sig_fast(zf) * cp + sig_fast(zi) * tanh_fast(zg);
        const float h = sig_fast(zo) * tanh_fast(c2);
        cbuf[brow * 512 + col] = c2;
        hout[brow * 512 + col] = f2b(h);
        if (hout2) hout2[brow * 1024 + col] = f2b(h);
    }
}

// ------------------------------------------------------------ attention logits
__global__ __launch_bounds__(256) void att_logits(
    const ushort* __restrict__ fproj, const float* __restrict__ HP,
    const float* __restrict__ waf, float* __restrict__ attL) {
    __shared__ float hpS[31][512];
    __shared__ float waS[512];
    __shared__ float accS[128][33];
    const int tid = threadIdx.x;
    const int b = blockIdx.x >> 1, ph = blockIdx.x & 1;
    const int pl = tid & 127, ch = tid >> 7;
    const int p = ph * 128 + pl;
    for (int i = tid; i < 31 * 512; i += 256) {
        const int tt = i >> 9, c = i & 511;
        hpS[tt][c] = HP[((size_t)tt * 128 + b) * 512 + c];
    }
    waS[tid] = waf[tid];
    if (tid < 256) waS[256 + tid] = waf[256 + tid];
    __syncthreads();
    float acc[31];
#pragma unroll
    for (int tt = 0; tt < 31; ++tt) acc[tt] = 0.f;
    const ushort* frow = fproj + (size_t)(b * 256 + p) * 512 + ch * 256;
    for (int c8 = 0; c8 < 32; ++c8) {
        const int cc = ch * 256 + c8 * 8;
        const uint4 fv = *(const uint4*)(frow + c8 * 8);
        float f[8];
        f[0] = b2f((unsigned short)(fv.x & 0xffff)); f[1] = b2f((unsigned short)(fv.x >> 16));
        f[2] = b2f((unsigned short)(fv.y & 0xffff)); f[3] = b2f((unsigned short)(fv.y >> 16));
        f[4] = b2f((unsigned short)(fv.z & 0xffff)); f[5] = b2f((unsigned short)(fv.z >> 16));
        f[6] = b2f((unsigned short)(fv.w & 0xffff)); f[7] = b2f((unsigned short)(fv.w >> 16));
        float w8[8];
#pragma unroll
        for (int j = 0; j < 8; ++j) w8[j] = waS[cc + j];
#pragma unroll
        for (int tt = 0; tt < 31; ++tt) {
            const float* hp8 = &hpS[tt][cc];   // wave-uniform -> broadcast
            float s = 0.f;
#pragma unroll
            for (int j = 0; j < 8; ++j)
                s += tanh_fast(f[j] + hp8[j]) * w8[j];
            acc[tt] += s;
        }
    }
    if (ch == 1) {
#pragma unroll
        for (int tt = 0; tt < 31; ++tt) accS[pl][tt] = acc[tt];
    }
    __syncthreads();
    if (ch == 0) {
#pragma unroll
        for (int tt = 0; tt < 31; ++tt)
            attL[((size_t)tt * 128 + b) * 256 + p] = acc[tt] + accS[pl][tt];
    }
}

// ------------------------------------------------------------ glimpse (+softmax)
__global__ __launch_bounds__(256) void glimpse_kernel(
    const ushort* __restrict__ featPad, const float* __restrict__ attL,
    ushort* __restrict__ HG) {
    __shared__ float attS[31][256];
    const int tid = threadIdx.x;
    const int b = blockIdx.x >> 1, chh = blockIdx.x & 1;
    const int c0 = chh << 8;
    const int w = tid >> 6, lane = tid & 63;
    for (int i = tid; i < 31 * 256; i += 256) {
        const int tt = i >> 8, p = i & 255;
        attS[tt][p] = attL[((size_t)tt * 128 + b) * 256 + p];
    }
    __syncthreads();
    for (int tt = w; tt < 31; tt += 4) {
        float v0 = attS[tt][lane], v1 = attS[tt][lane + 64];
        float v2 = attS[tt][lane + 128], v3 = attS[tt][lane + 192];
        float mx = fmaxf(fmaxf(v0, v1), fmaxf(v2, v3));
#pragma unroll
        for (int m = 1; m < 64; m <<= 1) mx = fmaxf(mx, __shfl_xor(mx, m));
        const float e0 = expf(v0 - mx), e1 = expf(v1 - mx);
        const float e2 = expf(v2 - mx), e3 = expf(v3 - mx);
        float s = e0 + e1 + e2 + e3;
#pragma unroll
        for (int m = 1; m < 64; m <<= 1) s += __shfl_xor(s, m);
        const float r = 1.0f / s;
        attS[tt][lane] = e0 * r;  attS[tt][lane + 64] = e1 * r;
        attS[tt][lane + 128] = e2 * r;  attS[tt][lane + 192] = e3 * r;
    }
    __syncthreads();
    float acc[31];
#pragma unroll
    for (int tt = 0; tt < 31; ++tt) acc[tt] = 0.f;
    for (int p = 0; p < 256; ++p) {
        const size_t fi = (((size_t)(b * 10 + (p >> 5) + 1) * 34 + (p & 31) + 1) << 9) + c0 + tid;
        const float fv = b2f(featPad[fi]);
#pragma unroll
        for (int tt = 0; tt < 31; ++tt) acc[tt] += fv * attS[tt][p];
    }
#pragma unroll
    for (int tt = 0; tt < 31; ++tt)
        HG[((size_t)tt * 128 + b) * 1024 + 512 + c0 + tid] = f2b(acc[tt]);
}

// ------------------------------------------------------------ logits store
__global__ __launch_bounds__(256) void logits_store(
    const float* __restrict__ C, const float* __restrict__ outBf,
    void* __restrict__ out, const int* __restrict__ flag) {
    const int i = blockIdx.x * 256 + threadIdx.x;
    if (i >= 3968 * 111) return;
    const int r = i / 111, v = i - r * 111;
    const int tt = r >> 7, b = r & 127;
    const float a = C[(size_t)r * 128 + v] + outBf[v];
    const size_t oi = ((size_t)b * 31 + tt) * 111 + v;
    if (*flag) ((float*)out)[oi] = a;
    else       ((ushort*)out)[oi] = f2b(a);
}

// ------------------------------------------------------------ launch
extern "C" void kernel_launch(void* const* d_in, const int* in_sizes, int n_in,
                              void* d_out, int out_size, void* d_ws, size_t ws_size,
                              hipStream_t stream) {
    (void)in_sizes; (void)n_in; (void)out_size;
    const void* features = d_in[0];
    const void* holistic = d_in[1];
    const int*  gt       = (const int*)d_in[2];
    const void* embed_W  = d_in[3];
    const void* k0 = d_in[4];
    const void* rk0 = d_in[5];
    const void* b0 = d_in[6];
    const void* k1 = d_in[7];
    const void* rk1 = d_in[8];
    const void* b1 = d_in[9];
    const void* Wh = d_in[10];
    const void* Wf = d_in[11];
    const void* bfv = d_in[12];
    const void* wa = d_in[13];
    const void* outW = d_in[14];
    const void* outB = d_in[15];

    char* ws = (char*)d_ws;
    size_t off = 0;
    auto take = [&](size_t bytes) -> char* {
        char* p = ws + off;
        off += (bytes + 255) & ~(size_t)255;
        return p;
    };
    int*    flag    = (int*)take(256);
    ushort* featPad = (ushort*)take(128ull * 10 * 34 * 512 * 2);   // 44.6 MB
    ushort* holB  = (ushort*)take(65536ull * 2);
    ushort* embB  = (ushort*)take(56832ull * 2);
    float*  b0f   = (float*)take(2048ull * 4);
    float*  b1f   = (float*)take(2048ull * 4);
    float*  bff   = (float*)take(512ull * 4);
    float*  waf   = (float*)take(512ull * 4);
    float*  outBf = (float*)take(111ull * 4);
    float*  outWf = (float*)take(113664ull * 4);
    ushort* fproj = (ushort*)take(32768ull * 512 * 2);             // 33.5 MB
    ushort* WfT   = (ushort*)take(4608ull * 512 * 2);
    ushort* k0T   = (ushort*)take(2048ull * 512 * 2);
    ushort* rk0T  = (ushort*)take(2048ull * 512 * 2);
    ushort* k1T   = (ushort*)take(2048ull * 512 * 2);
    ushort* rk1T  = (ushort*)take(2048ull * 512 * 2);
    ushort* WhT   = (ushort*)take(512ull * 512 * 2);
    float*  E0    = (float*)take(111ull * 2048 * 4);
    ushort* h0b0  = (ushort*)take(128ull * 512 * 2);
    ushort* h0b1  = (ushort*)take(128ull * 512 * 2);
    ushort* h1b0  = (ushort*)take(128ull * 512 * 2);
    ushort* h1b1  = (ushort*)take(128ull * 512 * 2);
    float*  c0buf = (float*)take(128ull * 512 * 4);
    float*  c1buf = (float*)take(128ull * 512 * 4);
    ushort* HG    = (ushort*)take(3968ull * 1024 * 2);             // [H1 | glimpse]
    float*  HP    = (float*)take(3968ull * 512 * 4);
    float*  attL  = (float*)take(31ull * 128 * 256 * 4);
    float*  Cout   = (float*)attL;                                  // alias (stream-serial)
    ushort* WoTpad = (ushort*)((char*)attL + 3968ull * 128 * 4);
    if (off > ws_size) return;

    // 0) dtype detect + canonicalize
    detect_dtype<<<dim3(1), dim3(64), 0, stream>>>(features, flag);
    build_featpad<<<dim3(87040), dim3(256), 0, stream>>>(features, featPad, flag);
    cvt_bf16<<<dim3(256), dim3(256), 0, stream>>>(holistic, holB, 65536, flag);
    cvt_bf16<<<dim3(222), dim3(256), 0, stream>>>(embed_W, embB, 56832, flag);
    cvt_f32<<<dim3(8), dim3(256), 0, stream>>>(b0, b0f, 2048, flag);
    cvt_f32<<<dim3(8), dim3(256), 0, stream>>>(b1, b1f, 2048, flag);
    cvt_f32<<<dim3(2), dim3(256), 0, stream>>>(bfv, bff, 512, flag);
    cvt_f32<<<dim3(2), dim3(256), 0, stream>>>(wa, waf, 512, flag);
    cvt_f32<<<dim3(1), dim3(256), 0, stream>>>(outB, outBf, 111, flag);
    cvt_f32<<<dim3(444), dim3(256), 0, stream>>>(outW, outWf, 113664, flag);
    // 1) weight transposes
    transpose_any<<<dim3(16 * 64), dim3(256), 0, stream>>>(k0, k0T, 512, 2048, flag);
    transpose_any<<<dim3(16 * 64), dim3(256), 0, stream>>>(rk0, rk0T, 512, 2048, flag);
    transpose_any<<<dim3(16 * 64), dim3(256), 0, stream>>>(k1, k1T, 512, 2048, flag);
    transpose_any<<<dim3(16 * 64), dim3(256), 0, stream>>>(rk1, rk1T, 512, 2048, flag);
    transpose_any<<<dim3(16 * 16), dim3(256), 0, stream>>>(Wh, WhT, 512, 512, flag);
    transpose_any<<<dim3(144 * 16), dim3(256), 0, stream>>>(Wf, WfT, 4608, 512, flag);
    // 2) conv fproj
    conv_fproj<<<dim3(1024), dim3(256), 0, stream>>>(featPad, WfT, bff, fproj);
    // 3) E0 = embed_W @ k0
    gemm_bt<<<dim3(16), dim3(256), 0, stream>>>(embB, k0T, E0, 111, 2048, 512, 512);
    // 4) recurrence: 34 lean dispatches
    for (int t = -2; t <= 31; ++t)
        lstm_stage<<<dim3(128), dim3(256), 0, stream>>>(t, holB, gt, b0f, b1f,
            k0T, rk0T, k1T, rk1T, E0, h0b0, h0b1, h1b0, h1b1, c0buf, c1buf, HG);
    // 5) batched epilogue
    gemm_bt<<<dim3(31 * 4), dim3(256), 0, stream>>>(HG, WhT, HP, 3968, 512, 512, 1024);
    att_logits<<<dim3(256), dim3(256), 0, stream>>>(fproj, HP, waf, attL);
    glimpse_kernel<<<dim3(256), dim3(256), 0, stream>>>(featPad, attL, HG);
    woT_build<<<dim3(512), dim3(256), 0, stream>>>(outWf, WoTpad);
    gemm_bt<<<dim3(31), dim3(256), 0, stream>>>(HG, WoTpad, Cout, 3968, 128, 1024, 1024);
    logits_store<<<dim3(1721), dim3(256), 0, stream>>>(Cout, outBf, d_out, flag);
}

// Round 6
// 995.884 us; speedup vs baseline: 1.7629x; 1.3942x over previous
//
#include <hip/hip_runtime.h>

// SARDecoder on MI355X (gfx950). Dtype-robust (runtime bf16-vs-fp32 detect).
//
// Round-6 changes:
//  - lstm_stage v3: 256 blocks, 32x16-per-gate tiles; A staged to LDS once
//    (padded rows, 2-way=free); B register-prefetched 2 k-blocks deep from
//    global; ZERO k-loop barriers (2 barriers per dispatch total)
//  - att_logits v2: t split in halves -> grid 512, 43 KB LDS -> 2 blocks/CU

typedef __bf16 bf16;
typedef bf16 bf16x8 __attribute__((ext_vector_type(8)));
typedef float f32x4 __attribute__((ext_vector_type(4)));

#define MFMA16(a, b, c) __builtin_amdgcn_mfma_f32_16x16x32_bf16((a), (b), (c), 0, 0, 0)

__device__ __forceinline__ float b2f(unsigned short u) {
    return __uint_as_float(((unsigned int)u) << 16);
}
__device__ __forceinline__ unsigned short f2b(float f) {
    unsigned int x = __float_as_uint(f);
    unsigned int r = (x + 0x7fffu + ((x >> 16) & 1u)) >> 16;   // RNE
    return (unsigned short)r;
}
__device__ __forceinline__ float tanh_fast(float x) {
    const float e = exp2f(2.885390082f * x);                   // 2/ln2
    return 1.0f - 2.0f * __builtin_amdgcn_rcpf(e + 1.0f);
}
__device__ __forceinline__ float sig_fast(float x) {
    return __builtin_amdgcn_rcpf(1.0f + exp2f(-1.44269504f * x));
}
// async 16B/lane global->LDS. lds dest is wave-uniform base + lane*16.
__device__ __forceinline__ void gl16(const ushort* g, ushort* l) {
    __builtin_amdgcn_global_load_lds(
        (const __attribute__((address_space(1))) void*)g,
        (__attribute__((address_space(3))) void*)l, 16, 0, 0);
}

// ------------------------------------------------------------ dtype detect
__global__ void detect_dtype(const void* __restrict__ feat, int* __restrict__ flag) {
    if (threadIdx.x == 0 && blockIdx.x == 0) {
        const ushort* u = (const ushort*)feat;
        int cnt = 0;
        for (int i = 0; i < 128; i += 2) {
            const int e = (u[i] >> 7) & 0xFF;
            if (e >= 96 && e <= 150) ++cnt;
        }
        *flag = (cnt >= 40) ? 0 : 1;
    }
}

// ------------------------------------------------------------ converters
__global__ __launch_bounds__(256) void cvt_bf16(
    const void* __restrict__ src, ushort* __restrict__ dst, int n,
    const int* __restrict__ flag) {
    const int i = blockIdx.x * 256 + threadIdx.x;
    if (i >= n) return;
    if (*flag) dst[i] = f2b(((const float*)src)[i]);
    else       dst[i] = ((const ushort*)src)[i];
}

__global__ __launch_bounds__(256) void cvt_f32(
    const void* __restrict__ src, float* __restrict__ dst, int n,
    const int* __restrict__ flag) {
    const int i = blockIdx.x * 256 + threadIdx.x;
    if (i >= n) return;
    if (*flag) dst[i] = ((const float*)src)[i];
    else       dst[i] = b2f(((const ushort*)src)[i]);
}

// ------------------------------------------------------------ padded features
// featPad[b][y][x][c], y:0..9, x:0..33 (1-halo, zero borders), bf16
__global__ __launch_bounds__(256) void build_featpad(
    const void* __restrict__ feat, ushort* __restrict__ featPad,
    const int* __restrict__ flag) {
    const int i = blockIdx.x * 256 + threadIdx.x;
    if (i >= 128 * 10 * 34 * 512) return;
    const int c = i & 511;
    const int xy = i >> 9;
    const int x = xy % 34;
    const int t2 = xy / 34;
    const int y = t2 % 10;
    const int b = t2 / 10;
    ushort v = 0;
    if (y >= 1 && y <= 8 && x >= 1 && x <= 32) {
        const size_t si = ((size_t)((b * 8 + y - 1) * 32 + (x - 1)) << 9) + c;
        v = *flag ? f2b(((const float*)feat)[si]) : ((const ushort*)feat)[si];
    }
    featPad[i] = v;
}

// ------------------------------------------------------------ transpose
__global__ __launch_bounds__(256) void transpose_any(
    const void* __restrict__ in, ushort* __restrict__ out, int R, int C,
    const int* __restrict__ flag) {
    __shared__ float s[32][33];
    const int f32 = *flag;
    const int nbc = C >> 5;
    const int rb = blockIdx.x / nbc, cb = blockIdx.x % nbc;
    const int tx = threadIdx.x & 31, ty = threadIdx.x >> 5;
#pragma unroll
    for (int k = 0; k < 4; ++k) {
        const size_t idx = (size_t)(rb * 32 + ty + k * 8) * C + cb * 32 + tx;
        s[ty + k * 8][tx] = f32 ? ((const float*)in)[idx] : b2f(((const ushort*)in)[idx]);
    }
    __syncthreads();
#pragma unroll
    for (int k = 0; k < 4; ++k)
        out[(size_t)(cb * 32 + ty + k * 8) * R + rb * 32 + tx] = f2b(s[tx][ty + k * 8]);
}

// ------------------------------------------------------------ outW^T pad
__global__ __launch_bounds__(256) void woT_build(
    const float* __restrict__ outWf, ushort* __restrict__ WoTpad) {
    const int i = blockIdx.x * 256 + threadIdx.x;
    if (i >= 131072) return;
    const int v = i >> 10, k = i & 1023;
    WoTpad[i] = (v < 111) ? f2b(outWf[k * 111 + v]) : (ushort)0;
}

// ------------------------------------------------------------ conv fproj
// M=32768 rows (b*256+p), N=512, K=9*512 tap-major. Staging via
// global_load_lds(16B) with XOR-swizzled LDS (round-4 win, kept).
__global__ __launch_bounds__(256) void conv_fproj(
    const ushort* __restrict__ featPad, const ushort* __restrict__ WfT,
    const float* __restrict__ bff, ushort* __restrict__ fproj) {
    __shared__ __align__(16) ushort As[128 * 64];
    __shared__ __align__(16) ushort Bs[128 * 64];
    const int tid = threadIdx.x;
    const int nb = blockIdx.x >> 8;          // 4 col-blocks (outer)
    const int rb = blockIdx.x & 255;         // 256 row-blocks
    const int b = rb >> 1, p0 = (rb & 1) << 7;
    const int w = tid >> 6, lane = tid & 63, l15 = lane & 15, q = lane >> 4;
    const int wr = (w >> 1) << 6, wc = (w & 1) << 6;
    const int chunkoff = (((lane & 7) ^ (lane >> 3)) << 3);   // swizzled gmem chunk
    int aoff[4], boff[4];
#pragma unroll
    for (int i = 0; i < 4; ++i) {
        const int r = w * 32 + (lane >> 3) + i * 8;
        const int p = p0 + r;
        const int yy = p >> 5, xx = p & 31;
        aoff[i] = (((b * 10 + yy) * 34 + xx) << 9) + chunkoff;
        boff[i] = (nb * 128 + r) * 4608 + chunkoff;
    }
    const int swa = l15 & 7;
    f32x4 acc[4][4] = {};
    for (int kb = 0; kb < 72; ++kb) {
        const int tap = kb >> 3;
        const int dy = tap / 3, dx = tap - dy * 3;
        const int koffA = ((dy * 34 + dx) << 9) + ((kb & 7) << 6);
        const int koffB = kb * 64;
        __syncthreads();
#pragma unroll
        for (int i = 0; i < 4; ++i) {
            gl16(featPad + aoff[i] + koffA, &As[(w * 32 + i * 8) * 64]);
            gl16(WfT + boff[i] + koffB, &Bs[(w * 32 + i * 8) * 64]);
        }
        __syncthreads();
#pragma unroll
        for (int ks = 0; ks < 64; ks += 32) {
            const int cq = (ks >> 3) + q;
            const int col = ((cq ^ swa) << 3);
            bf16x8 af[4], bfr[4];
#pragma unroll
            for (int i = 0; i < 4; ++i) af[i] = *(const bf16x8*)&As[(wr + i * 16 + l15) * 64 + col];
#pragma unroll
            for (int j = 0; j < 4; ++j) bfr[j] = *(const bf16x8*)&Bs[(wc + j * 16 + l15) * 64 + col];
#pragma unroll
            for (int i = 0; i < 4; ++i)
#pragma unroll
                for (int j = 0; j < 4; ++j)
                    acc[i][j] = MFMA16(af[i], bfr[j], acc[i][j]);
        }
    }
    const int rowbase = rb * 128 + wr, colbase = nb * 128 + wc;
#pragma unroll
    for (int i = 0; i < 4; ++i)
#pragma unroll
        for (int j = 0; j < 4; ++j)
#pragma unroll
            for (int rr = 0; rr < 4; ++rr) {
                const int row = rowbase + i * 16 + q * 4 + rr;
                const int col = colbase + j * 16 + l15;
                fproj[(size_t)row * 512 + col] = f2b(acc[i][j][rr] + bff[col]);
            }
}

// ------------------------------------------------------------ generic GEMM
__global__ __launch_bounds__(256) void gemm_bt(
    const ushort* __restrict__ A, const ushort* __restrict__ BT,
    float* __restrict__ C, int M, int N, int K, int lda) {
    __shared__ __align__(16) bf16 As[128][72];
    __shared__ __align__(16) bf16 Bs[128][72];
    const int tid = threadIdx.x;
    const int nnb = N >> 7;
    const int rb = blockIdx.x / nnb, nb = blockIdx.x % nnb;
    const int ar = tid >> 1, ah = (tid & 1) << 5;
    const int w = tid >> 6, lane = tid & 63, l15 = lane & 15, q = lane >> 4;
    const int wr = (w >> 1) << 6, wc = (w & 1) << 6;
    const int r_glob = rb * 128 + ar;
    const bool aval = (r_glob < M);
    const int r_ld = aval ? r_glob : 0;
    f32x4 acc[4][4] = {};
    const int nkb = K >> 6;
    for (int kb = 0; kb < nkb; ++kb) {
        const uint4 z4 = {0u, 0u, 0u, 0u};
        const uint4* asrc = (const uint4*)(A + (size_t)r_ld * lda + kb * 64 + ah);
        uint4 a0 = asrc[0], a1 = asrc[1], a2 = asrc[2], a3 = asrc[3];
        if (!aval) { a0 = z4; a1 = z4; a2 = z4; a3 = z4; }
        const uint4* bsrc = (const uint4*)(BT + (size_t)(nb * 128 + ar) * K + kb * 64 + ah);
        uint4 b0v = bsrc[0], b1v = bsrc[1], b2v = bsrc[2], b3v = bsrc[3];
        __syncthreads();
        *(uint4*)&As[ar][ah] = a0;
        *(uint4*)&As[ar][ah + 8] = a1;
        *(uint4*)&As[ar][ah + 16] = a2;
        *(uint4*)&As[ar][ah + 24] = a3;
        *(uint4*)&Bs[ar][ah] = b0v;
        *(uint4*)&Bs[ar][ah + 8] = b1v;
        *(uint4*)&Bs[ar][ah + 16] = b2v;
        *(uint4*)&Bs[ar][ah + 24] = b3v;
        __syncthreads();
#pragma unroll
        for (int ks = 0; ks < 64; ks += 32) {
            bf16x8 af[4], bfr[4];
#pragma unroll
            for (int i = 0; i < 4; ++i) af[i] = *(const bf16x8*)&As[wr + i * 16 + l15][ks + q * 8];
#pragma unroll
            for (int j = 0; j < 4; ++j) bfr[j] = *(const bf16x8*)&Bs[wc + j * 16 + l15][ks + q * 8];
#pragma unroll
            for (int i = 0; i < 4; ++i)
#pragma unroll
                for (int j = 0; j < 4; ++j)
                    acc[i][j] = MFMA16(af[i], bfr[j], acc[i][j]);
        }
    }
#pragma unroll
    for (int i = 0; i < 4; ++i)
#pragma unroll
        for (int j = 0; j < 4; ++j)
#pragma unroll
            for (int rr = 0; rr < 4; ++rr) {
                const int row = rb * 128 + wr + i * 16 + q * 4 + rr;
                const int col = nb * 128 + wc + j * 16 + l15;
                if (row < M) C[(size_t)row * N + col] = acc[i][j][rr];
            }
}

// ------------------------------------------------------------ LSTM stage v3
// grid 256. blocks 0..127: stage0 of step t; 128..255: stage1 of step t-1.
// Tile: 32 rows x 16 cols per gate (wave = gate). A staged to LDS once
// (row pad +8 -> 2-way conflicts = free); B register-prefetched 2 k-blocks
// deep from global. No barriers in the K loop.
__global__ __launch_bounds__(256) void lstm_stage(
    int t,
    const ushort* __restrict__ holistic, const int* __restrict__ gt,
    const float* __restrict__ b0f, const float* __restrict__ b1f,
    const ushort* __restrict__ k0T, const ushort* __restrict__ rk0T,
    const ushort* __restrict__ k1T, const ushort* __restrict__ rk1T,
    const float* __restrict__ E0,
    ushort* h0b0, ushort* h0b1, ushort* h1b0, ushort* h1b1,
    float* c0buf, float* c1buf, ushort* HG) {
    const int part = blockIdx.x >> 7;
    const int bi = blockIdx.x & 127;
    const ushort *A1 = nullptr, *A2 = nullptr, *B1 = nullptr, *B2 = nullptr;
    const float* bias = nullptr;
    ushort *hout = nullptr, *hout2 = nullptr;
    float* cbuf = nullptr;
    bool useC = false, useE = false;
    if (part == 0) {
        if (!(t == -2 || (t >= 0 && t <= 30))) return;
        bias = b0f; cbuf = c0buf;
        if (t == -2) { A1 = holistic; B1 = k0T; hout = h0b1; }
        else {
            A1 = ((t + 1) & 1) ? h0b1 : h0b0;
            B1 = rk0T;
            hout = (t & 1) ? h0b1 : h0b0;
            useC = true; useE = true;
        }
    } else {
        if (!(t == -1 || (t >= 1 && t <= 31))) return;
        bias = b1f; cbuf = c1buf;
        if (t == -1) { A1 = h0b1; B1 = k1T; hout = h1b1; }
        else {
            const int s = t - 1;
            A1 = (s & 1) ? h0b1 : h0b0;           // h0 of step s
            A2 = ((s + 1) & 1) ? h1b1 : h1b0;     // h1 of step s-1
            B1 = k1T; B2 = rk1T;
            hout = (s & 1) ? h1b1 : h1b0;
            hout2 = HG + (size_t)s * 131072;      // row stride 1024
            useC = true;
        }
    }
    const int m0 = (bi >> 5) << 5;      // 4 groups of 32 rows
    const int cc0 = (bi & 31) << 4;     // 32 chunks of 16 cols (per gate)
    const int tid = threadIdx.x;
    const int w = tid >> 6, lane = tid & 63, l15 = lane & 15, q = lane >> 4;
    __shared__ __align__(16) ushort As1[32 * 520];   // pad 8: 2-way = free
    __shared__ __align__(16) ushort As2[32 * 520];
    __shared__ float zs[4][32][17];
    // ---- stage A tiles once (coalesced)
#pragma unroll
    for (int it = 0; it < 8; ++it) {
        const int idx = tid + it * 256;
        const int row = idx >> 6, chv = idx & 63;
        *(uint4*)&As1[row * 520 + chv * 8] =
            *(const uint4*)(A1 + (size_t)(m0 + row) * 512 + chv * 8);
    }
    if (A2) {
#pragma unroll
        for (int it = 0; it < 8; ++it) {
            const int idx = tid + it * 256;
            const int row = idx >> 6, chv = idx & 63;
            *(uint4*)&As2[row * 520 + chv * 8] =
                *(const uint4*)(A2 + (size_t)(m0 + row) * 512 + chv * 8);
        }
    }
    __syncthreads();
    const int nkb = A2 ? 16 : 8;
    // ---- barrier-free K loop, B register-prefetched 2 deep
    const size_t brow = (size_t)(w * 512 + cc0 + l15) * 512 + q * 8;
    auto bp = [&](int kb) -> const ushort* {
        const ushort* base = (kb < 8) ? B1 : B2;
        return base + brow + (kb & 7) * 64;
    };
    bf16x8 c0v = *(const bf16x8*)bp(0);
    bf16x8 c1v = *(const bf16x8*)(bp(0) + 32);
    bf16x8 n0v = *(const bf16x8*)bp(1);
    bf16x8 n1v = *(const bf16x8*)(bp(1) + 32);
    f32x4 acc0 = {}, acc1 = {};
    for (int kb = 0; kb < nkb; ++kb) {
        const bf16x8 p0 = c0v, p1 = c1v;
        c0v = n0v; c1v = n1v;
        if (kb + 2 < nkb) {
            n0v = *(const bf16x8*)bp(kb + 2);
            n1v = *(const bf16x8*)(bp(kb + 2) + 32);
        }
        const ushort* asrc = (kb < 8) ? As1 : As2;
        const int kk = (kb & 7) * 64 + q * 8;
        bf16x8 a00 = *(const bf16x8*)&asrc[l15 * 520 + kk];
        bf16x8 a10 = *(const bf16x8*)&asrc[(16 + l15) * 520 + kk];
        bf16x8 a01 = *(const bf16x8*)&asrc[l15 * 520 + kk + 32];
        bf16x8 a11 = *(const bf16x8*)&asrc[(16 + l15) * 520 + kk + 32];
        acc0 = MFMA16(a00, p0, acc0);
        acc1 = MFMA16(a10, p0, acc1);
        acc0 = MFMA16(a01, p1, acc0);
        acc1 = MFMA16(a11, p1, acc1);
    }
    // ---- z tiles to LDS, then fused LSTM pointwise
#pragma unroll
    for (int rr = 0; rr < 4; ++rr) {
        zs[w][q * 4 + rr][l15] = acc0[rr];
        zs[w][16 + q * 4 + rr][l15] = acc1[rr];
    }
    __syncthreads();
#pragma unroll
    for (int it = 0; it < 2; ++it) {
        const int e = tid + it * 256;          // 512 = 32 rows x 16 cols
        const int mm = e >> 4, cc = e & 15;
        const int brow2 = m0 + mm, col = cc0 + cc;
        float zi = zs[0][mm][cc] + bias[col];
        float zf = zs[1][mm][cc] + bias[512 + col];
        float zg = zs[2][mm][cc] + bias[1024 + col];
        float zo = zs[3][mm][cc] + bias[1536 + col];
        if (useE) {
            const int s = (t == 0) ? 111 : gt[brow2 * 31 + t - 1];
            if (s >= 0 && s < 111) {
                const float* er = E0 + (size_t)s * 2048;
                zi += er[col]; zf += er[512 + col]; zg += er[1024 + col]; zo += er[1536 + col];
            }
        }
        const float cp = useC ? cbuf[brow2 * 512 + col] : 0.0f;
        const float c2 = sig_fast(zf) * cp + sig_fast(zi) * tanh_fast(zg);
        const float h = sig_fast(zo) * tanh_fast(c2);
        cbuf[brow2 * 512 + col] = c2;
        hout[brow2 * 512 + col] = f2b(h);
        if (hout2) hout2[brow2 * 1024 + col] = f2b(h);
    }
}

// ------------------------------------------------------------ attention logits v2
// attL[t,b,p] = sum_c tanh(fproj[b,p,c] + HP[t,b,c]) * wa[c]
// grid 512 = (b, p-half, t-half). Lane owns p; c serial -> hpS reads are
// wave-uniform broadcasts. 43 KB LDS -> 2 blocks/CU.
__global__ __launch_bounds__(256) void att_logits(
    const ushort* __restrict__ fproj, const float* __restrict__ HP,
    const float* __restrict__ waf, float* __restrict__ attL) {
    __shared__ float hpS[16][512];        // 32 KB
    __shared__ float waS[512];            // 2 KB
    __shared__ float accS[128][17];       // 8.7 KB
    const int tid = threadIdx.x;
    const int b = blockIdx.x >> 2, ph = (blockIdx.x >> 1) & 1, th = blockIdx.x & 1;
    const int t0 = th << 4, tc = th ? 15 : 16;
    const int pl = tid & 127, ch = tid >> 7;
    const int p = ph * 128 + pl;
    for (int i = tid; i < 16 * 512; i += 256) {
        const int tt = i >> 9, c = i & 511;
        hpS[tt][c] = (tt < tc) ? HP[((size_t)(t0 + tt) * 128 + b) * 512 + c] : 0.0f;
    }
    waS[tid] = waf[tid];
    if (tid < 256) waS[256 + tid] = waf[256 + tid];
    __syncthreads();
    float acc[16];
#pragma unroll
    for (int tt = 0; tt < 16; ++tt) acc[tt] = 0.f;
    const ushort* frow = fproj + (size_t)(b * 256 + p) * 512 + ch * 256;
    for (int c8 = 0; c8 < 32; ++c8) {
        const int cc = ch * 256 + c8 * 8;
        const uint4 fv = *(const uint4*)(frow + c8 * 8);
        float f[8];
        f[0] = b2f((unsigned short)(fv.x & 0xffff)); f[1] = b2f((unsigned short)(fv.x >> 16));
        f[2] = b2f((unsigned short)(fv.y & 0xffff)); f[3] = b2f((unsigned short)(fv.y >> 16));
        f[4] = b2f((unsigned short)(fv.z & 0xffff)); f[5] = b2f((unsigned short)(fv.z >> 16));
        f[6] = b2f((unsigned short)(fv.w & 0xffff)); f[7] = b2f((unsigned short)(fv.w >> 16));
        float w8[8];
#pragma unroll
        for (int j = 0; j < 8; ++j) w8[j] = waS[cc + j];
#pragma unroll
        for (int tt = 0; tt < 16; ++tt) {
            const float* hp8 = &hpS[tt][cc];   // wave-uniform -> broadcast
            float s = 0.f;
#pragma unroll
            for (int j = 0; j < 8; ++j)
                s += tanh_fast(f[j] + hp8[j]) * w8[j];
            acc[tt] += s;
        }
    }
    if (ch == 1) {
#pragma unroll
        for (int tt = 0; tt < 16; ++tt) accS[pl][tt] = acc[tt];
    }
    __syncthreads();
    if (ch == 0) {
        for (int tt = 0; tt < tc; ++tt)
            attL[((size_t)(t0 + tt) * 128 + b) * 256 + p] = acc[tt] + accS[pl][tt];
    }
}

// ------------------------------------------------------------ glimpse (+softmax)
__global__ __launch_bounds__(256) void glimpse_kernel(
    const ushort* __restrict__ featPad, const float* __restrict__ attL,
    ushort* __restrict__ HG) {
    __shared__ float attS[31][256];
    const int tid = threadIdx.x;
    const int b = blockIdx.x >> 1, chh = blockIdx.x & 1;
    const int c0 = chh << 8;
    const int w = tid >> 6, lane = tid & 63;
    for (int i = tid; i < 31 * 256; i += 256) {
        const int tt = i >> 8, p = i & 255;
        attS[tt][p] = attL[((size_t)tt * 128 + b) * 256 + p];
    }
    __syncthreads();
    for (int tt = w; tt < 31; tt += 4) {
        float v0 = attS[tt][lane], v1 = attS[tt][lane + 64];
        float v2 = attS[tt][lane + 128], v3 = attS[tt][lane + 192];
        float mx = fmaxf(fmaxf(v0, v1), fmaxf(v2, v3));
#pragma unroll
        for (int m = 1; m < 64; m <<= 1) mx = fmaxf(mx, __shfl_xor(mx, m));
        const float e0 = expf(v0 - mx), e1 = expf(v1 - mx);
        const float e2 = expf(v2 - mx), e3 = expf(v3 - mx);
        float s = e0 + e1 + e2 + e3;
#pragma unroll
        for (int m = 1; m < 64; m <<= 1) s += __shfl_xor(s, m);
        const float r = 1.0f / s;
        attS[tt][lane] = e0 * r;  attS[tt][lane + 64] = e1 * r;
        attS[tt][lane + 128] = e2 * r;  attS[tt][lane + 192] = e3 * r;
    }
    __syncthreads();
    float acc[31];
#pragma unroll
    for (int tt = 0; tt < 31; ++tt) acc[tt] = 0.f;
    for (int p = 0; p < 256; ++p) {
        const size_t fi = (((size_t)(b * 10 + (p >> 5) + 1) * 34 + (p & 31) + 1) << 9) + c0 + tid;
        const float fv = b2f(featPad[fi]);
#pragma unroll
        for (int tt = 0; tt < 31; ++tt) acc[tt] += fv * attS[tt][p];
    }
#pragma unroll
    for (int tt = 0; tt < 31; ++tt)
        HG[((size_t)tt * 128 + b) * 1024 + 512 + c0 + tid] = f2b(acc[tt]);
}

// ------------------------------------------------------------ logits store
__global__ __launch_bounds__(256) void logits_store(
    const float* __restrict__ C, const float* __restrict__ outBf,
    void* __restrict__ out, const int* __restrict__ flag) {
    const int i = blockIdx.x * 256 + threadIdx.x;
    if (i >= 3968 * 111) return;
    const int r = i / 111, v = i - r * 111;
    const int tt = r >> 7, b = r & 127;
    const float a = C[(size_t)r * 128 + v] + outBf[v];
    const size_t oi = ((size_t)b * 31 + tt) * 111 + v;
    if (*flag) ((float*)out)[oi] = a;
    else       ((ushort*)out)[oi] = f2b(a);
}

// ------------------------------------------------------------ launch
extern "C" void kernel_launch(void* const* d_in, const int* in_sizes, int n_in,
                              void* d_out, int out_size, void* d_ws, size_t ws_size,
                              hipStream_t stream) {
    (void)in_sizes; (void)n_in; (void)out_size;
    const void* features = d_in[0];
    const void* holistic = d_in[1];
    const int*  gt       = (const int*)d_in[2];
    const void* embed_W  = d_in[3];
    const void* k0 = d_in[4];
    const void* rk0 = d_in[5];
    const void* b0 = d_in[6];
    const void* k1 = d_in[7];
    const void* rk1 = d_in[8];
    const void* b1 = d_in[9];
    const void* Wh = d_in[10];
    const void* Wf = d_in[11];
    const void* bfv = d_in[12];
    const void* wa = d_in[13];
    const void* outW = d_in[14];
    const void* outB = d_in[15];

    char* ws = (char*)d_ws;
    size_t off = 0;
    auto take = [&](size_t bytes) -> char* {
        char* p = ws + off;
        off += (bytes + 255) & ~(size_t)255;
        return p;
    };
    int*    flag    = (int*)take(256);
    ushort* featPad = (ushort*)take(128ull * 10 * 34 * 512 * 2);   // 44.6 MB
    ushort* holB  = (ushort*)take(65536ull * 2);
    ushort* embB  = (ushort*)take(56832ull * 2);
    float*  b0f   = (float*)take(2048ull * 4);
    float*  b1f   = (float*)take(2048ull * 4);
    float*  bff   = (float*)take(512ull * 4);
    float*  waf   = (float*)take(512ull * 4);
    float*  outBf = (float*)take(111ull * 4);
    float*  outWf = (float*)take(113664ull * 4);
    ushort* fproj = (ushort*)take(32768ull * 512 * 2);             // 33.5 MB
    ushort* WfT   = (ushort*)take(4608ull * 512 * 2);
    ushort* k0T   = (ushort*)take(2048ull * 512 * 2);
    ushort* rk0T  = (ushort*)take(2048ull * 512 * 2);
    ushort* k1T   = (ushort*)take(2048ull * 512 * 2);
    ushort* rk1T  = (ushort*)take(2048ull * 512 * 2);
    ushort* WhT   = (ushort*)take(512ull * 512 * 2);
    float*  E0    = (float*)take(111ull * 2048 * 4);
    ushort* h0b0  = (ushort*)take(128ull * 512 * 2);
    ushort* h0b1  = (ushort*)take(128ull * 512 * 2);
    ushort* h1b0  = (ushort*)take(128ull * 512 * 2);
    ushort* h1b1  = (ushort*)take(128ull * 512 * 2);
    float*  c0buf = (float*)take(128ull * 512 * 4);
    float*  c1buf = (float*)take(128ull * 512 * 4);
    ushort* HG    = (ushort*)take(3968ull * 1024 * 2);             // [H1 | glimpse]
    float*  HP    = (float*)take(3968ull * 512 * 4);
    float*  attL  = (float*)take(31ull * 128 * 256 * 4);
    float*  Cout   = (float*)attL;                                  // alias (stream-serial)
    ushort* WoTpad = (ushort*)((char*)attL + 3968ull * 128 * 4);
    if (off > ws_size) return;

    // 0) dtype detect + canonicalize
    detect_dtype<<<dim3(1), dim3(64), 0, stream>>>(features, flag);
    build_featpad<<<dim3(87040), dim3(256), 0, stream>>>(features, featPad, flag);
    cvt_bf16<<<dim3(256), dim3(256), 0, stream>>>(holistic, holB, 65536, flag);
    cvt_bf16<<<dim3(222), dim3(256), 0, stream>>>(embed_W, embB, 56832, flag);
    cvt_f32<<<dim3(8), dim3(256), 0, stream>>>(b0, b0f, 2048, flag);
    cvt_f32<<<dim3(8), dim3(256), 0, stream>>>(b1, b1f, 2048, flag);
    cvt_f32<<<dim3(2), dim3(256), 0, stream>>>(bfv, bff, 512, flag);
    cvt_f32<<<dim3(2), dim3(256), 0, stream>>>(wa, waf, 512, flag);
    cvt_f32<<<dim3(1), dim3(256), 0, stream>>>(outB, outBf, 111, flag);
    cvt_f32<<<dim3(444), dim3(256), 0, stream>>>(outW, outWf, 113664, flag);
    // 1) weight transposes
    transpose_any<<<dim3(16 * 64), dim3(256), 0, stream>>>(k0, k0T, 512, 2048, flag);
    transpose_any<<<dim3(16 * 64), dim3(256), 0, stream>>>(rk0, rk0T, 512, 2048, flag);
    transpose_any<<<dim3(16 * 64), dim3(256), 0, stream>>>(k1, k1T, 512, 2048, flag);
    transpose_any<<<dim3(16 * 64), dim3(256), 0, stream>>>(rk1, rk1T, 512, 2048, flag);
    transpose_any<<<dim3(16 * 16), dim3(256), 0, stream>>>(Wh, WhT, 512, 512, flag);
    transpose_any<<<dim3(144 * 16), dim3(256), 0, stream>>>(Wf, WfT, 4608, 512, flag);
    // 2) conv fproj
    conv_fproj<<<dim3(1024), dim3(256), 0, stream>>>(featPad, WfT, bff, fproj);
    // 3) E0 = embed_W @ k0
    gemm_bt<<<dim3(16), dim3(256), 0, stream>>>(embB, k0T, E0, 111, 2048, 512, 512);
    // 4) recurrence: 34 lean dispatches (256 blocks each)
    for (int t = -2; t <= 31; ++t)
        lstm_stage<<<dim3(256), dim3(256), 0, stream>>>(t, holB, gt, b0f, b1f,
            k0T, rk0T, k1T, rk1T, E0, h0b0, h0b1, h1b0, h1b1, c0buf, c1buf, HG);
    // 5) batched epilogue
    gemm_bt<<<dim3(31 * 4), dim3(256), 0, stream>>>(HG, WhT, HP, 3968, 512, 512, 1024);
    att_logits<<<dim3(512), dim3(256), 0, stream>>>(fproj, HP, waf, attL);
    glimpse_kernel<<<dim3(256), dim3(256), 0, stream>>>(featPad, attL, HG);
    woT_build<<<dim3(512), dim3(256), 0, stream>>>(outWf, WoTpad);
    gemm_bt<<<dim3(31), dim3(256), 0, stream>>>(HG, WoTpad, Cout, 3968, 128, 1024, 1024);
    logits_store<<<dim3(1721), dim3(256), 0, stream>>>(Cout, outBf, d_out, flag);
}

// Round 7
// 933.363 us; speedup vs baseline: 1.8809x; 1.0670x over previous
//
#include <hip/hip_runtime.h>

// SARDecoder on MI355X (gfx950). Dtype-robust (runtime bf16-vs-fp32 detect).
//
// Round-7 changes:
//  - raw v_exp_f32 (inline asm) everywhere: libm exp2f emits range-fixup code
//  - att_logits v3: tanh sum strength-reduced to sumW - 2*sum(rcp(e+1)*w),
//    2.885 prescaled into hpS/f, -2w prescaled into waS; float4 hp/wa reads
//  - glimpse: attention weights transposed to [p][36] -> ds_read_b128
//  - lstm_stage: B prefetch 3-deep (L2 ~200cyc > 2-deep cover)

typedef __bf16 bf16;
typedef bf16 bf16x8 __attribute__((ext_vector_type(8)));
typedef float f32x4 __attribute__((ext_vector_type(4)));

#define MFMA16(a, b, c) __builtin_amdgcn_mfma_f32_16x16x32_bf16((a), (b), (c), 0, 0, 0)

__device__ __forceinline__ float b2f(unsigned short u) {
    return __uint_as_float(((unsigned int)u) << 16);
}
__device__ __forceinline__ unsigned short f2b(float f) {
    unsigned int x = __float_as_uint(f);
    unsigned int r = (x + 0x7fffu + ((x >> 16) & 1u)) >> 16;   // RNE
    return (unsigned short)r;
}
// raw v_exp_f32: no libm range fixups (gfx9 HW interlocks cover trans latency)
__device__ __forceinline__ float exp2_raw(float x) {
    float r;
    asm("v_exp_f32 %0, %1" : "=v"(r) : "v"(x));
    return r;
}
__device__ __forceinline__ float tanh_fast(float x) {
    const float e = exp2_raw(2.885390082f * x);                // 2/ln2
    return 1.0f - 2.0f * __builtin_amdgcn_rcpf(e + 1.0f);
}
__device__ __forceinline__ float sig_fast(float x) {
    return __builtin_amdgcn_rcpf(1.0f + exp2_raw(-1.44269504f * x));
}
// async 16B/lane global->LDS. lds dest is wave-uniform base + lane*16.
__device__ __forceinline__ void gl16(const ushort* g, ushort* l) {
    __builtin_amdgcn_global_load_lds(
        (const __attribute__((address_space(1))) void*)g,
        (__attribute__((address_space(3))) void*)l, 16, 0, 0);
}

// ------------------------------------------------------------ dtype detect
__global__ void detect_dtype(const void* __restrict__ feat, int* __restrict__ flag) {
    if (threadIdx.x == 0 && blockIdx.x == 0) {
        const ushort* u = (const ushort*)feat;
        int cnt = 0;
        for (int i = 0; i < 128; i += 2) {
            const int e = (u[i] >> 7) & 0xFF;
            if (e >= 96 && e <= 150) ++cnt;
        }
        *flag = (cnt >= 40) ? 0 : 1;
    }
}

// ------------------------------------------------------------ converters
__global__ __launch_bounds__(256) void cvt_bf16(
    const void* __restrict__ src, ushort* __restrict__ dst, int n,
    const int* __restrict__ flag) {
    const int i = blockIdx.x * 256 + threadIdx.x;
    if (i >= n) return;
    if (*flag) dst[i] = f2b(((const float*)src)[i]);
    else       dst[i] = ((const ushort*)src)[i];
}

__global__ __launch_bounds__(256) void cvt_f32(
    const void* __restrict__ src, float* __restrict__ dst, int n,
    const int* __restrict__ flag) {
    const int i = blockIdx.x * 256 + threadIdx.x;
    if (i >= n) return;
    if (*flag) dst[i] = ((const float*)src)[i];
    else       dst[i] = b2f(((const ushort*)src)[i]);
}

// ------------------------------------------------------------ padded features
// featPad[b][y][x][c], y:0..9, x:0..33 (1-halo, zero borders), bf16
__global__ __launch_bounds__(256) void build_featpad(
    const void* __restrict__ feat, ushort* __restrict__ featPad,
    const int* __restrict__ flag) {
    const int i = blockIdx.x * 256 + threadIdx.x;
    if (i >= 128 * 10 * 34 * 512) return;
    const int c = i & 511;
    const int xy = i >> 9;
    const int x = xy % 34;
    const int t2 = xy / 34;
    const int y = t2 % 10;
    const int b = t2 / 10;
    ushort v = 0;
    if (y >= 1 && y <= 8 && x >= 1 && x <= 32) {
        const size_t si = ((size_t)((b * 8 + y - 1) * 32 + (x - 1)) << 9) + c;
        v = *flag ? f2b(((const float*)feat)[si]) : ((const ushort*)feat)[si];
    }
    featPad[i] = v;
}

// ------------------------------------------------------------ transpose
__global__ __launch_bounds__(256) void transpose_any(
    const void* __restrict__ in, ushort* __restrict__ out, int R, int C,
    const int* __restrict__ flag) {
    __shared__ float s[32][33];
    const int f32 = *flag;
    const int nbc = C >> 5;
    const int rb = blockIdx.x / nbc, cb = blockIdx.x % nbc;
    const int tx = threadIdx.x & 31, ty = threadIdx.x >> 5;
#pragma unroll
    for (int k = 0; k < 4; ++k) {
        const size_t idx = (size_t)(rb * 32 + ty + k * 8) * C + cb * 32 + tx;
        s[ty + k * 8][tx] = f32 ? ((const float*)in)[idx] : b2f(((const ushort*)in)[idx]);
    }
    __syncthreads();
#pragma unroll
    for (int k = 0; k < 4; ++k)
        out[(size_t)(cb * 32 + ty + k * 8) * R + rb * 32 + tx] = f2b(s[tx][ty + k * 8]);
}

// ------------------------------------------------------------ outW^T pad
__global__ __launch_bounds__(256) void woT_build(
    const float* __restrict__ outWf, ushort* __restrict__ WoTpad) {
    const int i = blockIdx.x * 256 + threadIdx.x;
    if (i >= 131072) return;
    const int v = i >> 10, k = i & 1023;
    WoTpad[i] = (v < 111) ? f2b(outWf[k * 111 + v]) : (ushort)0;
}

// ------------------------------------------------------------ conv fproj
// M=32768 rows (b*256+p), N=512, K=9*512 tap-major. Staging via
// global_load_lds(16B) with XOR-swizzled LDS (round-4 win, kept).
__global__ __launch_bounds__(256) void conv_fproj(
    const ushort* __restrict__ featPad, const ushort* __restrict__ WfT,
    const float* __restrict__ bff, ushort* __restrict__ fproj) {
    __shared__ __align__(16) ushort As[128 * 64];
    __shared__ __align__(16) ushort Bs[128 * 64];
    const int tid = threadIdx.x;
    const int nb = blockIdx.x >> 8;          // 4 col-blocks (outer)
    const int rb = blockIdx.x & 255;         // 256 row-blocks
    const int b = rb >> 1, p0 = (rb & 1) << 7;
    const int w = tid >> 6, lane = tid & 63, l15 = lane & 15, q = lane >> 4;
    const int wr = (w >> 1) << 6, wc = (w & 1) << 6;
    const int chunkoff = (((lane & 7) ^ (lane >> 3)) << 3);   // swizzled gmem chunk
    int aoff[4], boff[4];
#pragma unroll
    for (int i = 0; i < 4; ++i) {
        const int r = w * 32 + (lane >> 3) + i * 8;
        const int p = p0 + r;
        const int yy = p >> 5, xx = p & 31;
        aoff[i] = (((b * 10 + yy) * 34 + xx) << 9) + chunkoff;
        boff[i] = (nb * 128 + r) * 4608 + chunkoff;
    }
    const int swa = l15 & 7;
    f32x4 acc[4][4] = {};
    for (int kb = 0; kb < 72; ++kb) {
        const int tap = kb >> 3;
        const int dy = tap / 3, dx = tap - dy * 3;
        const int koffA = ((dy * 34 + dx) << 9) + ((kb & 7) << 6);
        const int koffB = kb * 64;
        __syncthreads();
#pragma unroll
        for (int i = 0; i < 4; ++i) {
            gl16(featPad + aoff[i] + koffA, &As[(w * 32 + i * 8) * 64]);
            gl16(WfT + boff[i] + koffB, &Bs[(w * 32 + i * 8) * 64]);
        }
        __syncthreads();
#pragma unroll
        for (int ks = 0; ks < 64; ks += 32) {
            const int cq = (ks >> 3) + q;
            const int col = ((cq ^ swa) << 3);
            bf16x8 af[4], bfr[4];
#pragma unroll
            for (int i = 0; i < 4; ++i) af[i] = *(const bf16x8*)&As[(wr + i * 16 + l15) * 64 + col];
#pragma unroll
            for (int j = 0; j < 4; ++j) bfr[j] = *(const bf16x8*)&Bs[(wc + j * 16 + l15) * 64 + col];
#pragma unroll
            for (int i = 0; i < 4; ++i)
#pragma unroll
                for (int j = 0; j < 4; ++j)
                    acc[i][j] = MFMA16(af[i], bfr[j], acc[i][j]);
        }
    }
    const int rowbase = rb * 128 + wr, colbase = nb * 128 + wc;
#pragma unroll
    for (int i = 0; i < 4; ++i)
#pragma unroll
        for (int j = 0; j < 4; ++j)
#pragma unroll
            for (int rr = 0; rr < 4; ++rr) {
                const int row = rowbase + i * 16 + q * 4 + rr;
                const int col = colbase + j * 16 + l15;
                fproj[(size_t)row * 512 + col] = f2b(acc[i][j][rr] + bff[col]);
            }
}

// ------------------------------------------------------------ generic GEMM
__global__ __launch_bounds__(256) void gemm_bt(
    const ushort* __restrict__ A, const ushort* __restrict__ BT,
    float* __restrict__ C, int M, int N, int K, int lda) {
    __shared__ __align__(16) bf16 As[128][72];
    __shared__ __align__(16) bf16 Bs[128][72];
    const int tid = threadIdx.x;
    const int nnb = N >> 7;
    const int rb = blockIdx.x / nnb, nb = blockIdx.x % nnb;
    const int ar = tid >> 1, ah = (tid & 1) << 5;
    const int w = tid >> 6, lane = tid & 63, l15 = lane & 15, q = lane >> 4;
    const int wr = (w >> 1) << 6, wc = (w & 1) << 6;
    const int r_glob = rb * 128 + ar;
    const bool aval = (r_glob < M);
    const int r_ld = aval ? r_glob : 0;
    f32x4 acc[4][4] = {};
    const int nkb = K >> 6;
    for (int kb = 0; kb < nkb; ++kb) {
        const uint4 z4 = {0u, 0u, 0u, 0u};
        const uint4* asrc = (const uint4*)(A + (size_t)r_ld * lda + kb * 64 + ah);
        uint4 a0 = asrc[0], a1 = asrc[1], a2 = asrc[2], a3 = asrc[3];
        if (!aval) { a0 = z4; a1 = z4; a2 = z4; a3 = z4; }
        const uint4* bsrc = (const uint4*)(BT + (size_t)(nb * 128 + ar) * K + kb * 64 + ah);
        uint4 b0v = bsrc[0], b1v = bsrc[1], b2v = bsrc[2], b3v = bsrc[3];
        __syncthreads();
        *(uint4*)&As[ar][ah] = a0;
        *(uint4*)&As[ar][ah + 8] = a1;
        *(uint4*)&As[ar][ah + 16] = a2;
        *(uint4*)&As[ar][ah + 24] = a3;
        *(uint4*)&Bs[ar][ah] = b0v;
        *(uint4*)&Bs[ar][ah + 8] = b1v;
        *(uint4*)&Bs[ar][ah + 16] = b2v;
        *(uint4*)&Bs[ar][ah + 24] = b3v;
        __syncthreads();
#pragma unroll
        for (int ks = 0; ks < 64; ks += 32) {
            bf16x8 af[4], bfr[4];
#pragma unroll
            for (int i = 0; i < 4; ++i) af[i] = *(const bf16x8*)&As[wr + i * 16 + l15][ks + q * 8];
#pragma unroll
            for (int j = 0; j < 4; ++j) bfr[j] = *(const bf16x8*)&Bs[wc + j * 16 + l15][ks + q * 8];
#pragma unroll
            for (int i = 0; i < 4; ++i)
#pragma unroll
                for (int j = 0; j < 4; ++j)
                    acc[i][j] = MFMA16(af[i], bfr[j], acc[i][j]);
        }
    }
#pragma unroll
    for (int i = 0; i < 4; ++i)
#pragma unroll
        for (int j = 0; j < 4; ++j)
#pragma unroll
            for (int rr = 0; rr < 4; ++rr) {
                const int row = rb * 128 + wr + i * 16 + q * 4 + rr;
                const int col = nb * 128 + wc + j * 16 + l15;
                if (row < M) C[(size_t)row * N + col] = acc[i][j][rr];
            }
}

// ------------------------------------------------------------ LSTM stage v3
// grid 256. blocks 0..127: stage0 of step t; 128..255: stage1 of step t-1.
// A staged to LDS once (pad 8 -> free); B register-prefetched 3 deep.
__global__ __launch_bounds__(256) void lstm_stage(
    int t,
    const ushort* __restrict__ holistic, const int* __restrict__ gt,
    const float* __restrict__ b0f, const float* __restrict__ b1f,
    const ushort* __restrict__ k0T, const ushort* __restrict__ rk0T,
    const ushort* __restrict__ k1T, const ushort* __restrict__ rk1T,
    const float* __restrict__ E0,
    ushort* h0b0, ushort* h0b1, ushort* h1b0, ushort* h1b1,
    float* c0buf, float* c1buf, ushort* HG) {
    const int part = blockIdx.x >> 7;
    const int bi = blockIdx.x & 127;
    const ushort *A1 = nullptr, *A2 = nullptr, *B1 = nullptr, *B2 = nullptr;
    const float* bias = nullptr;
    ushort *hout = nullptr, *hout2 = nullptr;
    float* cbuf = nullptr;
    bool useC = false, useE = false;
    if (part == 0) {
        if (!(t == -2 || (t >= 0 && t <= 30))) return;
        bias = b0f; cbuf = c0buf;
        if (t == -2) { A1 = holistic; B1 = k0T; hout = h0b1; }
        else {
            A1 = ((t + 1) & 1) ? h0b1 : h0b0;
            B1 = rk0T;
            hout = (t & 1) ? h0b1 : h0b0;
            useC = true; useE = true;
        }
    } else {
        if (!(t == -1 || (t >= 1 && t <= 31))) return;
        bias = b1f; cbuf = c1buf;
        if (t == -1) { A1 = h0b1; B1 = k1T; hout = h1b1; }
        else {
            const int s = t - 1;
            A1 = (s & 1) ? h0b1 : h0b0;           // h0 of step s
            A2 = ((s + 1) & 1) ? h1b1 : h1b0;     // h1 of step s-1
            B1 = k1T; B2 = rk1T;
            hout = (s & 1) ? h1b1 : h1b0;
            hout2 = HG + (size_t)s * 131072;      // row stride 1024
            useC = true;
        }
    }
    const int m0 = (bi >> 5) << 5;      // 4 groups of 32 rows
    const int cc0 = (bi & 31) << 4;     // 32 chunks of 16 cols (per gate)
    const int tid = threadIdx.x;
    const int w = tid >> 6, lane = tid & 63, l15 = lane & 15, q = lane >> 4;
    __shared__ __align__(16) ushort As1[32 * 520];   // pad 8: 2-way = free
    __shared__ __align__(16) ushort As2[32 * 520];
    __shared__ float zs[4][32][17];
    // ---- stage A tiles once (coalesced)
#pragma unroll
    for (int it = 0; it < 8; ++it) {
        const int idx = tid + it * 256;
        const int row = idx >> 6, chv = idx & 63;
        *(uint4*)&As1[row * 520 + chv * 8] =
            *(const uint4*)(A1 + (size_t)(m0 + row) * 512 + chv * 8);
    }
    if (A2) {
#pragma unroll
        for (int it = 0; it < 8; ++it) {
            const int idx = tid + it * 256;
            const int row = idx >> 6, chv = idx & 63;
            *(uint4*)&As2[row * 520 + chv * 8] =
                *(const uint4*)(A2 + (size_t)(m0 + row) * 512 + chv * 8);
        }
    }
    __syncthreads();
    const int nkb = A2 ? 16 : 8;
    // ---- barrier-free K loop, B register-prefetched 3 deep
    const size_t brow = (size_t)(w * 512 + cc0 + l15) * 512 + q * 8;
    auto bp = [&](int kb) -> const ushort* {
        const ushort* base = (kb < 8) ? B1 : B2;
        return base + brow + (kb & 7) * 64;
    };
    bf16x8 b0a = *(const bf16x8*)bp(0), b1a = *(const bf16x8*)(bp(0) + 32);
    bf16x8 b0b = *(const bf16x8*)bp(1), b1b = *(const bf16x8*)(bp(1) + 32);
    bf16x8 b0c = *(const bf16x8*)bp(2), b1c = *(const bf16x8*)(bp(2) + 32);
    f32x4 acc0 = {}, acc1 = {};
    for (int kb = 0; kb < nkb; ++kb) {
        const bf16x8 p0 = b0a, p1 = b1a;
        b0a = b0b; b1a = b1b; b0b = b0c; b1b = b1c;
        if (kb + 3 < nkb) {
            b0c = *(const bf16x8*)bp(kb + 3);
            b1c = *(const bf16x8*)(bp(kb + 3) + 32);
        }
        const ushort* asrc = (kb < 8) ? As1 : As2;
        const int kk = (kb & 7) * 64 + q * 8;
        bf16x8 a00 = *(const bf16x8*)&asrc[l15 * 520 + kk];
        bf16x8 a10 = *(const bf16x8*)&asrc[(16 + l15) * 520 + kk];
        bf16x8 a01 = *(const bf16x8*)&asrc[l15 * 520 + kk + 32];
        bf16x8 a11 = *(const bf16x8*)&asrc[(16 + l15) * 520 + kk + 32];
        acc0 = MFMA16(a00, p0, acc0);
        acc1 = MFMA16(a10, p0, acc1);
        acc0 = MFMA16(a01, p1, acc0);
        acc1 = MFMA16(a11, p1, acc1);
    }
    // ---- z tiles to LDS, then fused LSTM pointwise
#pragma unroll
    for (int rr = 0; rr < 4; ++rr) {
        zs[w][q * 4 + rr][l15] = acc0[rr];
        zs[w][16 + q * 4 + rr][l15] = acc1[rr];
    }
    __syncthreads();
#pragma unroll
    for (int it = 0; it < 2; ++it) {
        const int e = tid + it * 256;          // 512 = 32 rows x 16 cols
        const int mm = e >> 4, cc = e & 15;
        const int brow2 = m0 + mm, col = cc0 + cc;
        float zi = zs[0][mm][cc] + bias[col];
        float zf = zs[1][mm][cc] + bias[512 + col];
        float zg = zs[2][mm][cc] + bias[1024 + col];
        float zo = zs[3][mm][cc] + bias[1536 + col];
        if (useE) {
            const int s = (t == 0) ? 111 : gt[brow2 * 31 + t - 1];
            if (s >= 0 && s < 111) {
                const float* er = E0 + (size_t)s * 2048;
                zi += er[col]; zf += er[512 + col]; zg += er[1024 + col]; zo += er[1536 + col];
            }
        }
        const float cp = useC ? cbuf[brow2 * 512 + col] : 0.0f;
        const float c2 = sig_fast(zf) * cp + sig_fast(zi) * tanh_fast(zg);
        const float h = sig_fast(zo) * tanh_fast(c2);
        cbuf[brow2 * 512 + col] = c2;
        hout[brow2 * 512 + col] = f2b(h);
        if (hout2) hout2[brow2 * 1024 + col] = f2b(h);
    }
}

// ------------------------------------------------------------ attention logits v3
// attL[t,b,p] = sum_c tanh(fproj + HP) * wa
//            = sumW - 2 * sum_c rcp(exp2(2.885*(fproj+HP)) + 1) * wa[c]
// hpS prescaled by 2.885; waS holds -2*wa. 5-op inner loop, 2 trans.
__global__ __launch_bounds__(256) void att_logits(
    const ushort* __restrict__ fproj, const float* __restrict__ HP,
    const float* __restrict__ waf, float* __restrict__ attL) {
    __shared__ float hpS[16][512];        // 32 KB (prescaled by 2.885)
    __shared__ float waS[512];            // 2 KB (-2 * wa)
    __shared__ float accS[128][17];       // 8.7 KB
    const int tid = threadIdx.x;
    const int b = blockIdx.x >> 2, ph = (blockIdx.x >> 1) & 1, th = blockIdx.x & 1;
    const int t0 = th << 4, tc = th ? 15 : 16;
    const int pl = tid & 127, ch = tid >> 7;
    const int p = ph * 128 + pl;
    for (int i = tid; i < 16 * 512; i += 256) {
        const int tt = i >> 9, c = i & 511;
        hpS[tt][c] = (tt < tc) ? 2.885390082f * HP[((size_t)(t0 + tt) * 128 + b) * 512 + c] : 0.0f;
    }
    waS[tid] = -2.0f * waf[tid];
    if (tid < 256) waS[256 + tid] = -2.0f * waf[256 + tid];
    __syncthreads();
    // per-thread constant term: sum of wa over this thread's c-half
    float sumW = 0.f;
    {
        const float* wh = &waS[ch * 256];
        for (int c4 = 0; c4 < 64; ++c4) {
            const float4 wv = *(const float4*)&wh[c4 * 4];
            sumW += wv.x + wv.y + wv.z + wv.w;
        }
        sumW *= -0.5f;     // waS = -2w  ->  sum w = -0.5 * sum waS
    }
    float acc[16];
#pragma unroll
    for (int tt = 0; tt < 16; ++tt) acc[tt] = 0.f;
    const ushort* frow = fproj + (size_t)(b * 256 + p) * 512 + ch * 256;
    for (int c8 = 0; c8 < 32; ++c8) {
        const int cc = ch * 256 + c8 * 8;
        const uint4 fv = *(const uint4*)(frow + c8 * 8);
        float f[8];
        f[0] = b2f((unsigned short)(fv.x & 0xffff)); f[1] = b2f((unsigned short)(fv.x >> 16));
        f[2] = b2f((unsigned short)(fv.y & 0xffff)); f[3] = b2f((unsigned short)(fv.y >> 16));
        f[4] = b2f((unsigned short)(fv.z & 0xffff)); f[5] = b2f((unsigned short)(fv.z >> 16));
        f[6] = b2f((unsigned short)(fv.w & 0xffff)); f[7] = b2f((unsigned short)(fv.w >> 16));
#pragma unroll
        for (int j = 0; j < 8; ++j) f[j] *= 2.885390082f;
        const float4 w0 = *(const float4*)&waS[cc];      // -2w
        const float4 w1 = *(const float4*)&waS[cc + 4];
#pragma unroll
        for (int tt = 0; tt < 16; ++tt) {
            const float4 h0 = *(const float4*)&hpS[tt][cc];      // broadcast
            const float4 h1 = *(const float4*)&hpS[tt][cc + 4];
            float s = acc[tt];
            s = fmaf(__builtin_amdgcn_rcpf(exp2_raw(f[0] + h0.x) + 1.0f), w0.x, s);
            s = fmaf(__builtin_amdgcn_rcpf(exp2_raw(f[1] + h0.y) + 1.0f), w0.y, s);
            s = fmaf(__builtin_amdgcn_rcpf(exp2_raw(f[2] + h0.z) + 1.0f), w0.z, s);
            s = fmaf(__builtin_amdgcn_rcpf(exp2_raw(f[3] + h0.w) + 1.0f), w0.w, s);
            s = fmaf(__builtin_amdgcn_rcpf(exp2_raw(f[4] + h1.x) + 1.0f), w1.x, s);
            s = fmaf(__builtin_amdgcn_rcpf(exp2_raw(f[5] + h1.y) + 1.0f), w1.y, s);
            s = fmaf(__builtin_amdgcn_rcpf(exp2_raw(f[6] + h1.z) + 1.0f), w1.z, s);
            s = fmaf(__builtin_amdgcn_rcpf(exp2_raw(f[7] + h1.w) + 1.0f), w1.w, s);
            acc[tt] = s;
        }
    }
    if (ch == 1) {
#pragma unroll
        for (int tt = 0; tt < 16; ++tt) accS[pl][tt] = acc[tt] + sumW;
    }
    __syncthreads();
    if (ch == 0) {
        for (int tt = 0; tt < tc; ++tt)
            attL[((size_t)(t0 + tt) * 128 + b) * 256 + p] = acc[tt] + sumW + accS[pl][tt];
    }
}

// ------------------------------------------------------------ glimpse (+softmax)
// attT transposed [p][36] (16B-aligned pad) -> b128 broadcast reads in p-loop.
__global__ __launch_bounds__(256) void glimpse_kernel(
    const ushort* __restrict__ featPad, const float* __restrict__ attL,
    ushort* __restrict__ HG) {
    __shared__ __align__(16) float attT[256 * 36];   // 36.9 KB
    const int tid = threadIdx.x;
    const int b = blockIdx.x >> 1, chh = blockIdx.x & 1;
    const int c0 = chh << 8;
    const int w = tid >> 6, lane = tid & 63;
    for (int i = tid; i < 31 * 256; i += 256) {
        const int tt = i >> 8, p = i & 255;
        attT[p * 36 + tt] = attL[((size_t)tt * 128 + b) * 256 + p];
    }
    __syncthreads();
    for (int tt = w; tt < 31; tt += 4) {
        float v0 = attT[lane * 36 + tt], v1 = attT[(lane + 64) * 36 + tt];
        float v2 = attT[(lane + 128) * 36 + tt], v3 = attT[(lane + 192) * 36 + tt];
        float mx = fmaxf(fmaxf(v0, v1), fmaxf(v2, v3));
#pragma unroll
        for (int m = 1; m < 64; m <<= 1) mx = fmaxf(mx, __shfl_xor(mx, m));
        const float e0 = exp2_raw((v0 - mx) * 1.44269504f);
        const float e1 = exp2_raw((v1 - mx) * 1.44269504f);
        const float e2 = exp2_raw((v2 - mx) * 1.44269504f);
        const float e3 = exp2_raw((v3 - mx) * 1.44269504f);
        float s = e0 + e1 + e2 + e3;
#pragma unroll
        for (int m = 1; m < 64; m <<= 1) s += __shfl_xor(s, m);
        const float r = 1.0f / s;
        attT[lane * 36 + tt] = e0 * r;  attT[(lane + 64) * 36 + tt] = e1 * r;
        attT[(lane + 128) * 36 + tt] = e2 * r;  attT[(lane + 192) * 36 + tt] = e3 * r;
    }
    __syncthreads();
    float acc[31];
#pragma unroll
    for (int tt = 0; tt < 31; ++tt) acc[tt] = 0.f;
    for (int p = 0; p < 256; ++p) {
        const size_t fi = (((size_t)(b * 10 + (p >> 5) + 1) * 34 + (p & 31) + 1) << 9) + c0 + tid;
        const float fv = b2f(featPad[fi]);
        const float4 a0 = *(const float4*)&attT[p * 36];       // broadcast b128
        const float4 a1 = *(const float4*)&attT[p * 36 + 4];
        const float4 a2 = *(const float4*)&attT[p * 36 + 8];
        const float4 a3 = *(const float4*)&attT[p * 36 + 12];
        const float4 a4 = *(const float4*)&attT[p * 36 + 16];
        const float4 a5 = *(const float4*)&attT[p * 36 + 20];
        const float4 a6 = *(const float4*)&attT[p * 36 + 24];
        const float4 a7 = *(const float4*)&attT[p * 36 + 28];
        acc[0] = fmaf(fv, a0.x, acc[0]);   acc[1] = fmaf(fv, a0.y, acc[1]);
        acc[2] = fmaf(fv, a0.z, acc[2]);   acc[3] = fmaf(fv, a0.w, acc[3]);
        acc[4] = fmaf(fv, a1.x, acc[4]);   acc[5] = fmaf(fv, a1.y, acc[5]);
        acc[6] = fmaf(fv, a1.z, acc[6]);   acc[7] = fmaf(fv, a1.w, acc[7]);
        acc[8] = fmaf(fv, a2.x, acc[8]);   acc[9] = fmaf(fv, a2.y, acc[9]);
        acc[10] = fmaf(fv, a2.z, acc[10]); acc[11] = fmaf(fv, a2.w, acc[11]);
        acc[12] = fmaf(fv, a3.x, acc[12]); acc[13] = fmaf(fv, a3.y, acc[13]);
        acc[14] = fmaf(fv, a3.z, acc[14]); acc[15] = fmaf(fv, a3.w, acc[15]);
        acc[16] = fmaf(fv, a4.x, acc[16]); acc[17] = fmaf(fv, a4.y, acc[17]);
        acc[18] = fmaf(fv, a4.z, acc[18]); acc[19] = fmaf(fv, a4.w, acc[19]);
        acc[20] = fmaf(fv, a5.x, acc[20]); acc[21] = fmaf(fv, a5.y, acc[21]);
        acc[22] = fmaf(fv, a5.z, acc[22]); acc[23] = fmaf(fv, a5.w, acc[23]);
        acc[24] = fmaf(fv, a6.x, acc[24]); acc[25] = fmaf(fv, a6.y, acc[25]);
        acc[26] = fmaf(fv, a6.z, acc[26]); acc[27] = fmaf(fv, a6.w, acc[27]);
        acc[28] = fmaf(fv, a7.x, acc[28]); acc[29] = fmaf(fv, a7.y, acc[29]);
        acc[30] = fmaf(fv, a7.z, acc[30]);
    }
#pragma unroll
    for (int tt = 0; tt < 31; ++tt)
        HG[((size_t)tt * 128 + b) * 1024 + 512 + c0 + tid] = f2b(acc[tt]);
}

// ------------------------------------------------------------ logits store
__global__ __launch_bounds__(256) void logits_store(
    const float* __restrict__ C, const float* __restrict__ outBf,
    void* __restrict__ out, const int* __restrict__ flag) {
    const int i = blockIdx.x * 256 + threadIdx.x;
    if (i >= 3968 * 111) return;
    const int r = i / 111, v = i - r * 111;
    const int tt = r >> 7, b = r & 127;
    const float a = C[(size_t)r * 128 + v] + outBf[v];
    const size_t oi = ((size_t)b * 31 + tt) * 111 + v;
    if (*flag) ((float*)out)[oi] = a;
    else       ((ushort*)out)[oi] = f2b(a);
}

// ------------------------------------------------------------ launch
extern "C" void kernel_launch(void* const* d_in, const int* in_sizes, int n_in,
                              void* d_out, int out_size, void* d_ws, size_t ws_size,
                              hipStream_t stream) {
    (void)in_sizes; (void)n_in; (void)out_size;
    const void* features = d_in[0];
    const void* holistic = d_in[1];
    const int*  gt       = (const int*)d_in[2];
    const void* embed_W  = d_in[3];
    const void* k0 = d_in[4];
    const void* rk0 = d_in[5];
    const void* b0 = d_in[6];
    const void* k1 = d_in[7];
    const void* rk1 = d_in[8];
    const void* b1 = d_in[9];
    const void* Wh = d_in[10];
    const void* Wf = d_in[11];
    const void* bfv = d_in[12];
    const void* wa = d_in[13];
    const void* outW = d_in[14];
    const void* outB = d_in[15];

    char* ws = (char*)d_ws;
    size_t off = 0;
    auto take = [&](size_t bytes) -> char* {
        char* p = ws + off;
        off += (bytes + 255) & ~(size_t)255;
        return p;
    };
    int*    flag    = (int*)take(256);
    ushort* featPad = (ushort*)take(128ull * 10 * 34 * 512 * 2);   // 44.6 MB
    ushort* holB  = (ushort*)take(65536ull * 2);
    ushort* embB  = (ushort*)take(56832ull * 2);
    float*  b0f   = (float*)take(2048ull * 4);
    float*  b1f   = (float*)take(2048ull * 4);
    float*  bff   = (float*)take(512ull * 4);
    float*  waf   = (float*)take(512ull * 4);
    float*  outBf = (float*)take(111ull * 4);
    float*  outWf = (float*)take(113664ull * 4);
    ushort* fproj = (ushort*)take(32768ull * 512 * 2);             // 33.5 MB
    ushort* WfT   = (ushort*)take(4608ull * 512 * 2);
    ushort* k0T   = (ushort*)take(2048ull * 512 * 2);
    ushort* rk0T  = (ushort*)take(2048ull * 512 * 2);
    ushort* k1T   = (ushort*)take(2048ull * 512 * 2);
    ushort* rk1T  = (ushort*)take(2048ull * 512 * 2);
    ushort* WhT   = (ushort*)take(512ull * 512 * 2);
    float*  E0    = (float*)take(111ull * 2048 * 4);
    ushort* h0b0  = (ushort*)take(128ull * 512 * 2);
    ushort* h0b1  = (ushort*)take(128ull * 512 * 2);
    ushort* h1b0  = (ushort*)take(128ull * 512 * 2);
    ushort* h1b1  = (ushort*)take(128ull * 512 * 2);
    float*  c0buf = (float*)take(128ull * 512 * 4);
    float*  c1buf = (float*)take(128ull * 512 * 4);
    ushort* HG    = (ushort*)take(3968ull * 1024 * 2);             // [H1 | glimpse]
    float*  HP    = (float*)take(3968ull * 512 * 4);
    float*  attL  = (float*)take(31ull * 128 * 256 * 4);
    float*  Cout   = (float*)attL;                                  // alias (stream-serial)
    ushort* WoTpad = (ushort*)((char*)attL + 3968ull * 128 * 4);
    if (off > ws_size) return;

    // 0) dtype detect + canonicalize
    detect_dtype<<<dim3(1), dim3(64), 0, stream>>>(features, flag);
    build_featpad<<<dim3(87040), dim3(256), 0, stream>>>(features, featPad, flag);
    cvt_bf16<<<dim3(256), dim3(256), 0, stream>>>(holistic, holB, 65536, flag);
    cvt_bf16<<<dim3(222), dim3(256), 0, stream>>>(embed_W, embB, 56832, flag);
    cvt_f32<<<dim3(8), dim3(256), 0, stream>>>(b0, b0f, 2048, flag);
    cvt_f32<<<dim3(8), dim3(256), 0, stream>>>(b1, b1f, 2048, flag);
    cvt_f32<<<dim3(2), dim3(256), 0, stream>>>(bfv, bff, 512, flag);
    cvt_f32<<<dim3(2), dim3(256), 0, stream>>>(wa, waf, 512, flag);
    cvt_f32<<<dim3(1), dim3(256), 0, stream>>>(outB, outBf, 111, flag);
    cvt_f32<<<dim3(444), dim3(256), 0, stream>>>(outW, outWf, 113664, flag);
    // 1) weight transposes
    transpose_any<<<dim3(16 * 64), dim3(256), 0, stream>>>(k0, k0T, 512, 2048, flag);
    transpose_any<<<dim3(16 * 64), dim3(256), 0, stream>>>(rk0, rk0T, 512, 2048, flag);
    transpose_any<<<dim3(16 * 64), dim3(256), 0, stream>>>(k1, k1T, 512, 2048, flag);
    transpose_any<<<dim3(16 * 64), dim3(256), 0, stream>>>(rk1, rk1T, 512, 2048, flag);
    transpose_any<<<dim3(16 * 16), dim3(256), 0, stream>>>(Wh, WhT, 512, 512, flag);
    transpose_any<<<dim3(144 * 16), dim3(256), 0, stream>>>(Wf, WfT, 4608, 512, flag);
    // 2) conv fproj
    conv_fproj<<<dim3(1024), dim3(256), 0, stream>>>(featPad, WfT, bff, fproj);
    // 3) E0 = embed_W @ k0
    gemm_bt<<<dim3(16), dim3(256), 0, stream>>>(embB, k0T, E0, 111, 2048, 512, 512);
    // 4) recurrence: 34 lean dispatches (256 blocks each)
    for (int t = -2; t <= 31; ++t)
        lstm_stage<<<dim3(256), dim3(256), 0, stream>>>(t, holB, gt, b0f, b1f,
            k0T, rk0T, k1T, rk1T, E0, h0b0, h0b1, h1b0, h1b1, c0buf, c1buf, HG);
    // 5) batched epilogue
    gemm_bt<<<dim3(31 * 4), dim3(256), 0, stream>>>(HG, WhT, HP, 3968, 512, 512, 1024);
    att_logits<<<dim3(512), dim3(256), 0, stream>>>(fproj, HP, waf, attL);
    glimpse_kernel<<<dim3(256), dim3(256), 0, stream>>>(featPad, attL, HG);
    woT_build<<<dim3(512), dim3(256), 0, stream>>>(outWf, WoTpad);
    gemm_bt<<<dim3(31), dim3(256), 0, stream>>>(HG, WoTpad, Cout, 3968, 128, 1024, 1024);
    logits_store<<<dim3(1721), dim3(256), 0, stream>>>(Cout, outBf, d_out, flag);
}